// Round 6
// baseline (263.720 us; speedup 1.0000x reference)
//
#include <hip/hip_runtime.h>
#include <cstdint>
#include <cstddef>

#define IN_CH 128
#define HID_CH 128
#define OUT_CH 64
#define BSH 8        // nodes per bucket = 256
#define PB 4096      // edges per histogram/partition block

typedef unsigned int uint32;
typedef unsigned char uchar;
typedef short bf16x8 __attribute__((ext_vector_type(8)));
typedef float f32x4 __attribute__((ext_vector_type(4)));
typedef float f32x2 __attribute__((ext_vector_type(2)));

// float -> bf16 round-to-nearest-even
static __device__ __forceinline__ unsigned short f2bf(float f) {
    uint32 u = __float_as_uint(f);
    u += 0x7fffu + ((u >> 16) & 1u);
    return (unsigned short)(u >> 16);
}

// async global->LDS, 16B per lane, register-free (compiler cannot serialize)
typedef const __attribute__((address_space(1))) char gch;
typedef __attribute__((address_space(3))) char lch;
static __device__ __forceinline__ void gload16(const void* g, void* l) {
    __builtin_amdgcn_global_load_lds((gch*)g, (lch*)l, 16, 0, 0);
}

// ---------------- CSR build (bucketed, LDS-atomic only) ----------------

// bhist over buckets; wtrans fused into trailing blocks (independent work).
__global__ __launch_bounds__(256) void bhist_wtrans(
    const int* __restrict__ dst, int* __restrict__ bcnt, int E, int NB, int gP,
    const float* __restrict__ W1, const float* __restrict__ W2,
    unsigned short* __restrict__ W1t, unsigned short* __restrict__ W2t) {
    if (blockIdx.x >= (uint32)gP) {
        int t = (blockIdx.x - gP) * 256 + threadIdx.x;
        if (t < 128 * 128) {
            int nc = t >> 7, k = t & 127;
            W1t[t] = f2bf(W1[k * 128 + nc]);
        }
        int u = t - 128 * 128;
        if (u >= 0 && u < 64 * 128) {
            int nc = u >> 7, k = u & 127;
            W2t[u] = f2bf(W2[k * 64 + nc]);
        }
        return;
    }
    __shared__ int h[512];
    int t = threadIdx.x;
    int e0 = blockIdx.x * PB;
    int cnt = min(PB, E - e0);
    for (int b = t; b < NB; b += 256) h[b] = 0;
    __syncthreads();
    for (int i = t; i < cnt; i += 256)
        atomicAdd(&h[dst[e0 + i] >> BSH], 1);
    __syncthreads();
    for (int b = t; b < NB; b += 256)
        if (h[b]) atomicAdd(&bcnt[b], h[b]);
}

// cursors start at ZERO (part1 adds bbase[b] itself).
__global__ void bscan(const int* __restrict__ bcnt, int* __restrict__ bbase,
                      int* __restrict__ bcur, int NB, int E) {
    __shared__ int s[512];
    int t = threadIdx.x;
    int v = (t < NB) ? bcnt[t] : 0;
    s[t] = v;
    __syncthreads();
    for (int o = 1; o < 512; o <<= 1) {
        int add = (t >= o) ? s[t - o] : 0;
        __syncthreads();
        s[t] += add;
        __syncthreads();
    }
    if (t < NB) { bbase[t] = s[t] - v; bcur[t] = 0; }
    if (t == 0) bbase[NB] = E;
}

// part1: edges cached in LDS (single global read), histogram, then grouped write.
__global__ __launch_bounds__(256) void part1(
    const int* __restrict__ src, const int* __restrict__ dst,
    const int* __restrict__ bbase, int* __restrict__ bcur,
    int2* __restrict__ pairBuf, int E, int NB) {
    __shared__ int2 pairs[PB];          // 32 KB
    __shared__ int hist[512];
    __shared__ int base[512];
    int t = threadIdx.x;
    int e0 = blockIdx.x * PB;
    int cnt = min(PB, E - e0);
    for (int b = t; b < NB; b += 256) hist[b] = 0;
    __syncthreads();
    for (int i = t; i < cnt; i += 256) {
        int s = src[e0 + i], d = dst[e0 + i];
        pairs[i] = make_int2(s, d);
        atomicAdd(&hist[d >> BSH], 1);
    }
    __syncthreads();
    for (int b = t; b < NB; b += 256) {
        int h = hist[b];
        int gb = (h > 0) ? atomicAdd(&bcur[b], h) : 0;
        base[b] = bbase[b] + gb;
        hist[b] = 0;
    }
    __syncthreads();
    for (int i = t; i < cnt; i += 256) {
        int2 p = pairs[i];
        int b = p.y >> BSH;
        int q = base[b] + atomicAdd(&hist[b], 1);
        pairBuf[q] = p;
    }
}

__global__ __launch_bounds__(256) void bucket_build(
    const int2* __restrict__ pairBuf, const int* __restrict__ bbase,
    int* __restrict__ rowptr, int* __restrict__ deg, float* __restrict__ dinv,
    int* __restrict__ csr, int N) {
    __shared__ int cnt[256];
    __shared__ int loc[256];
    int b = blockIdx.x, t = threadIdx.x;
    int start = bbase[b], end = bbase[b + 1];
    cnt[t] = 0;
    __syncthreads();
    for (int i = start + t; i < end; i += 256)
        atomicAdd(&cnt[pairBuf[i].y & 255], 1);
    __syncthreads();
    int v = cnt[t];
    loc[t] = v;
    __syncthreads();
    for (int o = 1; o < 256; o <<= 1) {
        int add = (t >= o) ? loc[t - o] : 0;
        __syncthreads();
        loc[t] += add;
        __syncthreads();
    }
    int excl = loc[t] - v;
    int node = (b << BSH) + t;
    if (node < N) {
        rowptr[node] = start + excl;
        deg[node] = v;
        dinv[node] = rsqrtf((float)(v + 2));   // +2 self-loops
    }
    __syncthreads();
    cnt[t] = excl;                              // reuse as cursor
    __syncthreads();
    for (int i = start + t; i < end; i += 256) {
        int2 p = pairBuf[i];
        int q = start + atomicAdd(&cnt[p.y & 255], 1);
        csr[q] = p.x;
    }
}

// ---------------- MFMA GEMM1: H1[n,128] = fp8(dinv[n] * (x[n,128] @ W1)) ----------
// m97-style staging (global_load_lds width=16, register-free) + OPERAND-SWAPPED
// MFMA: acc[nt][p] holds 4 CONSECUTIVE channels of ONE node -> dword fp8 stores.

__global__ __launch_bounds__(256) void gemm1_mfma(
    const float* __restrict__ A, const unsigned short* __restrict__ Wt,
    const float* __restrict__ dinv, uchar* __restrict__ C, int n, int nTiles) {
    constexpr int NT = 8;                          // 128 out channels / 16
    __shared__ unsigned short Ws[128 * 136];       // padded W (34.8K)
    __shared__ char As[64 * 512];                  // 64-row fp32 tile (32K)

    const int t = threadIdx.x;

    // stage W once (padded pitch kills ds_read bank conflicts)
    for (int i = t; i < 128 * 16; i += 256) {
        int rr = i >> 4, sq = i & 15;
        *(uint4*)&Ws[rr * 136 + sq * 8] = *(const uint4*)(Wt + rr * 128 + sq * 8);
    }

    const int w = t >> 6, l = t & 63;
    const int q = l >> 4, r16 = l & 15;
    const int rw = w * 16 + r16;                   // this lane's node row in tile

    for (int tile = blockIdx.x; tile < nTiles; tile += gridDim.x) {
        const int row0 = tile * 64;

        // ---- stage A tile: linear LDS dest, per-lane clamped global source ----
#pragma unroll
        for (int rnd = 0; rnd < 8; rnd++) {
            int p = rnd * 4096 + t * 16;           // byte position in tile
            int row = row0 + (p >> 9);
            int col = p & 511;
            gload16((const char*)A + (size_t)min(row, n - 1) * 512 + col, As + p);
        }
        __syncthreads();   // drains vmcnt -> tile resident (and W on first iter)

        f32x4 acc[NT];
#pragma unroll
        for (int i = 0; i < NT; i++) acc[i] = (f32x4){0.f, 0.f, 0.f, 0.f};

#pragma unroll
        for (int s = 0; s < 4; s++) {
            const int k0 = s * 32 + q * 8;         // element k-offset
            // x-fragment (B operand: lane&15 -> node col)
            const float* Arow = (const float*)(As + rw * 512);
            float4 v0 = *(const float4*)(Arow + k0);
            float4 v1 = *(const float4*)(Arow + k0 + 4);
            bf16x8 xf;
            xf[0] = (short)f2bf(v0.x); xf[1] = (short)f2bf(v0.y);
            xf[2] = (short)f2bf(v0.z); xf[3] = (short)f2bf(v0.w);
            xf[4] = (short)f2bf(v1.x); xf[5] = (short)f2bf(v1.y);
            xf[6] = (short)f2bf(v1.z); xf[7] = (short)f2bf(v1.w);
#pragma unroll
            for (int nt = 0; nt < NT; nt++) {
                // W-fragment (A operand: lane&15 -> channel row)
                bf16x8 wf = *(const bf16x8*)&Ws[(nt * 16 + r16) * 136 + k0];
                acc[nt] = __builtin_amdgcn_mfma_f32_16x16x32_bf16(wf, xf, acc[nt], 0, 0, 0);
            }
        }

        // ---- epilogue: acc[nt][p] = channel (nt*16 + q*4 + p) of node rw ----
        const int node = row0 + rw;
        const bool nv = node < n;
        const float dv = dinv[min(node, n - 1)];
        uchar* Crow = C + (size_t)node * 128;
#pragma unroll
        for (int nt = 0; nt < NT; nt++) {
            int pk = 0;
            pk = __builtin_amdgcn_cvt_pk_fp8_f32(acc[nt][0] * dv, acc[nt][1] * dv, pk, false);
            pk = __builtin_amdgcn_cvt_pk_fp8_f32(acc[nt][2] * dv, acc[nt][3] * dv, pk, true);
            if (nv) *(uint32*)(Crow + nt * 16 + q * 4) = (uint32)pk;
        }
        __syncthreads();   // protect As from next tile's staging
    }
}

// ---------------- Fused agg1 + gemm2 -------------------------------------------
// Gather phase: 16-lane group per node; within the group, 8 lanes per edge
// (uint4 = 16 fp8 each) -> HALF the VMEM instructions of the old uint2 scheme,
// 128 B/lane in flight in the 8-slot unroll. A one-time shfl_xor(8) parity
// combine merges the two edge-subset accumulators per node.
// W2 MFMA fragments are preloaded at kernel ENTRY (consumed after the barrier,
// so their latency hides under the whole gather phase).

__global__ __launch_bounds__(256) void agg1_fused(
    const uchar* __restrict__ H, const int* __restrict__ csr,
    const int* __restrict__ rowptr, const int* __restrict__ deg,
    const float* __restrict__ dinv, const float* __restrict__ bias,
    const unsigned short* __restrict__ W2t, uchar* __restrict__ H2, int n) {
    __shared__ unsigned short tile[16 * 136];      // 16 nodes x 128ch bf16, padded
    int t = threadIdx.x;
    int g = t >> 4;                                 // node slot in block (0..15)
    int v = blockIdx.x * 16 + g;
    int hl = t & 15;
    int gsel = t & 48;
    bool valid = v < n;
    int vc = valid ? v : 0;
    int base = rowptr[vc];
    int cnt = valid ? deg[vc] : 0;
    const int par = hl >> 3;                        // edge parity (0/1)
    const uint32 co16 = (uint32)((hl & 7) * 16);    // byte offset of 16-ch window

    // ---- W2 fragment preload (hidden under gather) ----
    const int w = t >> 6, l = t & 63;
    const int q = l >> 4, r16 = l & 15;
    bf16x8 wf[4];
#pragma unroll
    for (int s = 0; s < 4; s++)
        wf[s] = *(const bf16x8*)(W2t + (size_t)(w * 16 + r16) * 128 + s * 32 + q * 8);

    f32x2 S0 = (f32x2){0.f, 0.f}, S1 = S0, S2 = S0, S3 = S0;
    f32x2 S4 = S0, S5 = S0, S6 = S0, S7 = S0;

#define ACCU4(h)                                                    \
    {                                                               \
        S0 += __builtin_amdgcn_cvt_pk_f32_fp8((h).x, false);        \
        S1 += __builtin_amdgcn_cvt_pk_f32_fp8((h).x, true);         \
        S2 += __builtin_amdgcn_cvt_pk_f32_fp8((h).y, false);        \
        S3 += __builtin_amdgcn_cvt_pk_f32_fp8((h).y, true);         \
        S4 += __builtin_amdgcn_cvt_pk_f32_fp8((h).z, false);        \
        S5 += __builtin_amdgcn_cvt_pk_f32_fp8((h).z, true);         \
        S6 += __builtin_amdgcn_cvt_pk_f32_fp8((h).w, false);        \
        S7 += __builtin_amdgcn_cvt_pk_f32_fp8((h).w, true);         \
    }

    for (int j0 = 0; j0 < cnt; j0 += 16) {
        int nj = min(16, cnt - j0);
        int ul = 0;
        if (hl < nj) ul = csr[base + j0 + hl];
        int j = 0;
        for (; j + 16 <= nj; j += 16) {            // 8 slots x 2 edges
            int u0 = __shfl(ul, (j + 0 + par) | gsel);
            int u1 = __shfl(ul, (j + 2 + par) | gsel);
            int u2 = __shfl(ul, (j + 4 + par) | gsel);
            int u3 = __shfl(ul, (j + 6 + par) | gsel);
            int u4 = __shfl(ul, (j + 8 + par) | gsel);
            int u5 = __shfl(ul, (j + 10 + par) | gsel);
            int u6 = __shfl(ul, (j + 12 + par) | gsel);
            int u7 = __shfl(ul, (j + 14 + par) | gsel);
            uint4 h0 = *(const uint4*)(H + (((uint32)u0 << 7) + co16));
            uint4 h1 = *(const uint4*)(H + (((uint32)u1 << 7) + co16));
            uint4 h2 = *(const uint4*)(H + (((uint32)u2 << 7) + co16));
            uint4 h3 = *(const uint4*)(H + (((uint32)u3 << 7) + co16));
            uint4 h4 = *(const uint4*)(H + (((uint32)u4 << 7) + co16));
            uint4 h5 = *(const uint4*)(H + (((uint32)u5 << 7) + co16));
            uint4 h6 = *(const uint4*)(H + (((uint32)u6 << 7) + co16));
            uint4 h7 = *(const uint4*)(H + (((uint32)u7 << 7) + co16));
            ACCU4(h0); ACCU4(h1); ACCU4(h2); ACCU4(h3);
            ACCU4(h4); ACCU4(h5); ACCU4(h6); ACCU4(h7);
        }
        for (; j + 2 <= nj; j += 2) {              // 1 slot x 2 edges
            int u = __shfl(ul, (j + par) | gsel);
            uint4 h = *(const uint4*)(H + (((uint32)u << 7) + co16));
            ACCU4(h);
        }
        if (j < nj) {                               // odd final edge: lanes par==0
            int u = __shfl(ul, j | gsel);
            if (par == 0) {
                uint4 h = *(const uint4*)(H + (((uint32)u << 7) + co16));
                ACCU4(h);
            }
        }
    }
#undef ACCU4

    // ---- combine parity halves (lane <-> lane^8 hold the same channels) ----
#define CMB8(S) { f32x2 T_; T_[0] = __shfl_xor(S[0], 8); T_[1] = __shfl_xor(S[1], 8); S += T_; }
    CMB8(S0); CMB8(S1); CMB8(S2); CMB8(S3); CMB8(S4); CMB8(S5); CMB8(S6); CMB8(S7);
#undef CMB8

    // ---- finish hidden: self-loop + bias + ReLU, pack 8 bf16 per lane ----
    // lane's output channels: cho = (hl&7)*16 + par*8  (regs S[par*4 .. par*4+3])
    uint4 pk = make_uint4(0, 0, 0, 0);
    if (valid) {
        float dv = dinv[vc];
        uint2 hv = *(const uint2*)(H + (((uint32)vc << 7) + co16 + (uint32)(par * 8)));
        f32x2 s0 = __builtin_amdgcn_cvt_pk_f32_fp8(hv.x, false);
        f32x2 s1 = __builtin_amdgcn_cvt_pk_f32_fp8(hv.x, true);
        f32x2 s2 = __builtin_amdgcn_cvt_pk_f32_fp8(hv.y, false);
        f32x2 s3 = __builtin_amdgcn_cvt_pk_f32_fp8(hv.y, true);
        const f32x2* bp = (const f32x2*)(bias + (hl & 7) * 16 + par * 8);
        f32x2 a0 = par ? S4 : S0, a1 = par ? S5 : S1;
        f32x2 a2 = par ? S6 : S2, a3 = par ? S7 : S3;
        f32x2 e0 = dv * (a0 + 2.f * s0) + bp[0];
        f32x2 e1 = dv * (a1 + 2.f * s1) + bp[1];
        f32x2 e2 = dv * (a2 + 2.f * s2) + bp[2];
        f32x2 e3 = dv * (a3 + 2.f * s3) + bp[3];
        float o0 = fmaxf(e0[0], 0.f), o1 = fmaxf(e0[1], 0.f);
        float o2 = fmaxf(e1[0], 0.f), o3 = fmaxf(e1[1], 0.f);
        float o4 = fmaxf(e2[0], 0.f), o5 = fmaxf(e2[1], 0.f);
        float o6 = fmaxf(e3[0], 0.f), o7 = fmaxf(e3[1], 0.f);
        pk.x = (uint32)f2bf(o0) | ((uint32)f2bf(o1) << 16);
        pk.y = (uint32)f2bf(o2) | ((uint32)f2bf(o3) << 16);
        pk.z = (uint32)f2bf(o4) | ((uint32)f2bf(o5) << 16);
        pk.w = (uint32)f2bf(o6) | ((uint32)f2bf(o7) << 16);
    }
    *(uint4*)&tile[g * 136 + (hl & 7) * 16 + par * 8] = pk;
    __syncthreads();

    // ---- gemm2 tail: wave w -> channels w*16..+15 for all 16 nodes ----
    f32x4 acc2 = (f32x4){0.f, 0.f, 0.f, 0.f};
#pragma unroll
    for (int s = 0; s < 4; s++) {
        bf16x8 hf = *(const bf16x8*)&tile[r16 * 136 + s * 32 + q * 8];     // node r16
        acc2 = __builtin_amdgcn_mfma_f32_16x16x32_bf16(wf[s], hf, acc2, 0, 0, 0);
    }
    const int node = blockIdx.x * 16 + r16;
    if (node < n) {
        const float dv2 = dinv[node];
        int pk2 = 0;
        pk2 = __builtin_amdgcn_cvt_pk_fp8_f32(acc2[0] * dv2, acc2[1] * dv2, pk2, false);
        pk2 = __builtin_amdgcn_cvt_pk_fp8_f32(acc2[2] * dv2, acc2[3] * dv2, pk2, true);
        *(uint32*)(H2 + (size_t)node * 64 + w * 16 + q * 4) = (uint32)pk2;
    }
}

// agg2: 64 ch; gather with 4 lanes/edge (uint4 = 16 fp8) -> 4 edges per slot,
// shfl_xor(4)+shfl_xor(8) combine; log_softmax within group of 16.
__global__ __launch_bounds__(256) void agg_lsm_64(
    const uchar* __restrict__ H, const int* __restrict__ csr,
    const int* __restrict__ rowptr, const int* __restrict__ deg,
    const float* __restrict__ dinv, const float* __restrict__ bias,
    float* __restrict__ out, int n) {
    int t = threadIdx.x;
    int v = blockIdx.x * 16 + (t >> 4);
    int hl = t & 15;
    int gsel = t & 48;
    bool valid = v < n;
    int vc = valid ? v : 0;
    int base = rowptr[vc];
    int cnt = valid ? deg[vc] : 0;
    const int par4 = hl >> 2;                       // edge sub-slot (0..3)
    const uint32 co16 = (uint32)((hl & 3) * 16);    // byte offset of 16-ch window

    f32x2 S0 = (f32x2){0.f, 0.f}, S1 = S0, S2 = S0, S3 = S0;
    f32x2 S4 = S0, S5 = S0, S6 = S0, S7 = S0;

#define ACCU4(h)                                                    \
    {                                                               \
        S0 += __builtin_amdgcn_cvt_pk_f32_fp8((h).x, false);        \
        S1 += __builtin_amdgcn_cvt_pk_f32_fp8((h).x, true);         \
        S2 += __builtin_amdgcn_cvt_pk_f32_fp8((h).y, false);        \
        S3 += __builtin_amdgcn_cvt_pk_f32_fp8((h).y, true);         \
        S4 += __builtin_amdgcn_cvt_pk_f32_fp8((h).z, false);        \
        S5 += __builtin_amdgcn_cvt_pk_f32_fp8((h).z, true);         \
        S6 += __builtin_amdgcn_cvt_pk_f32_fp8((h).w, false);        \
        S7 += __builtin_amdgcn_cvt_pk_f32_fp8((h).w, true);         \
    }

    for (int j0 = 0; j0 < cnt; j0 += 16) {
        int nj = min(16, cnt - j0);
        int ul = 0;
        if (hl < nj) ul = csr[base + j0 + hl];
        int j = 0;
        for (; j + 16 <= nj; j += 16) {            // 4 slots x 4 edges
            int u0 = __shfl(ul, (j + 0 + par4) | gsel);
            int u1 = __shfl(ul, (j + 4 + par4) | gsel);
            int u2 = __shfl(ul, (j + 8 + par4) | gsel);
            int u3 = __shfl(ul, (j + 12 + par4) | gsel);
            uint4 h0 = *(const uint4*)(H + (((uint32)u0 << 6) + co16));
            uint4 h1 = *(const uint4*)(H + (((uint32)u1 << 6) + co16));
            uint4 h2 = *(const uint4*)(H + (((uint32)u2 << 6) + co16));
            uint4 h3 = *(const uint4*)(H + (((uint32)u3 << 6) + co16));
            ACCU4(h0); ACCU4(h1); ACCU4(h2); ACCU4(h3);
        }
        for (; j + 4 <= nj; j += 4) {              // 1 slot x 4 edges
            int u = __shfl(ul, (j + par4) | gsel);
            uint4 h = *(const uint4*)(H + (((uint32)u << 6) + co16));
            ACCU4(h);
        }
        int rem = nj - j;
        if (rem) {
            int u = __shfl(ul, ((j + par4) & 15) | gsel);
            if (par4 < rem) {
                uint4 h = *(const uint4*)(H + (((uint32)u << 6) + co16));
                ACCU4(h);
            }
        }
    }
#undef ACCU4

    // ---- combine the 4 edge sub-slots (lanes hl, hl^4, hl^8, hl^12) ----
#define CMB(S, M) { f32x2 T_; T_[0] = __shfl_xor(S[0], M); T_[1] = __shfl_xor(S[1], M); S += T_; }
    CMB(S0, 4); CMB(S1, 4); CMB(S2, 4); CMB(S3, 4);
    CMB(S4, 4); CMB(S5, 4); CMB(S6, 4); CMB(S7, 4);
    CMB(S0, 8); CMB(S1, 8); CMB(S2, 8); CMB(S3, 8);
    CMB(S4, 8); CMB(S5, 8); CMB(S6, 8); CMB(S7, 8);
#undef CMB

    // lane's 4 output channels: off = (hl&3)*16 + par4*4 -> regs S[par4*2], S[par4*2+1]
    f32x2 a0 = (par4 == 0) ? S0 : (par4 == 1) ? S2 : (par4 == 2) ? S4 : S6;
    f32x2 a1 = (par4 == 0) ? S1 : (par4 == 1) ? S3 : (par4 == 2) ? S5 : S7;
    const uint32 off = co16 + (uint32)(par4 * 4);

    float dv = dinv[vc];
    uint32 hv = *(const uint32*)(H + (((uint32)vc << 6) + off));
    f32x2 s0 = __builtin_amdgcn_cvt_pk_f32_fp8(hv, false);
    f32x2 s1 = __builtin_amdgcn_cvt_pk_f32_fp8(hv, true);
    const f32x2* bp = (const f32x2*)(bias + off);
    f32x2 w0 = dv * (a0 + 2.f * s0) + bp[0];
    f32x2 w1 = dv * (a1 + 2.f * s1) + bp[1];
    float v0 = w0[0], v1 = w0[1], v2 = w1[0], v3 = w1[1];
    // log_softmax across the 64 channels held by this 16-lane group
    float m = fmaxf(fmaxf(v0, v1), fmaxf(v2, v3));
    for (int o = 8; o > 0; o >>= 1) m = fmaxf(m, __shfl_xor(m, o));
    float e = (__expf(v0 - m) + __expf(v1 - m)) + (__expf(v2 - m) + __expf(v3 - m));
    for (int o = 8; o > 0; o >>= 1) e += __shfl_xor(e, o);
    float ls = m + __logf(e);
    if (valid)
        *(float4*)(out + (size_t)vc * 64 + off) =
            make_float4(v0 - ls, v1 - ls, v2 - ls, v3 - ls);
}

// ---------------- launch ----------------

extern "C" void kernel_launch(void* const* d_in, const int* in_sizes, int n_in,
                              void* d_out, int out_size, void* d_ws, size_t ws_size,
                              hipStream_t stream) {
    const float* x  = (const float*)d_in[0];
    const int*   ei = (const int*)d_in[1];
    const float* W1 = (const float*)d_in[2];
    const float* b1 = (const float*)d_in[3];
    const float* W2 = (const float*)d_in[4];
    const float* b2 = (const float*)d_in[5];
    float* out = (float*)d_out;

    const int N = in_sizes[0] / IN_CH;  // 100000
    const int E = in_sizes[1] / 2;      // 1600000
    const int* src = ei;
    const int* dst = ei + E;
    const int NB = (N + 255) >> BSH;    // 391 buckets

    char* w = (char*)d_ws;
    size_t off = 0;
    auto alloc = [&](size_t bytes) -> char* {
        char* p = w + off;
        off = (off + bytes + 255) & ~(size_t)255;
        return p;
    };
    int*   deg    = (int*)alloc((size_t)N * 4);
    int*   rowptr = (int*)alloc((size_t)N * 4);
    int*   bcnt   = (int*)alloc(512 * 4);
    int*   bbase  = (int*)alloc(513 * 4);
    int*   bcur   = (int*)alloc(512 * 4);
    float* dinv   = (float*)alloc((size_t)N * 4 + 1024);  // +pad for vector tails
    int*   csr    = (int*)alloc((size_t)E * 4);
    unsigned short* W1t = (unsigned short*)alloc(128 * 128 * 2);
    unsigned short* W2t = (unsigned short*)alloc(64 * 128 * 2);
    uchar* H1  = (uchar*)alloc((size_t)N * HID_CH);          // fp8, 12.8 MB
    char*  scratch = alloc((size_t)E * 8);                   // pairBuf then H2
    uchar* H2  = (uchar*)scratch;        // fp8, 6.4 MB (pairBuf dead after bucket_build)
    int2*  pairBuf = (int2*)scratch;

    hipMemsetAsync(bcnt, 0, 512 * 4, stream);

    int gP = (E + PB - 1) / PB;         // 391 partition blocks

    bhist_wtrans<<<gP + 96, 256, 0, stream>>>(dst, bcnt, E, NB, gP, W1, W2, W1t, W2t);
    bscan<<<1, 512, 0, stream>>>(bcnt, bbase, bcur, NB, E);
    part1<<<gP, 256, 0, stream>>>(src, dst, bbase, bcur, pairBuf, E, NB);
    bucket_build<<<NB, 256, 0, stream>>>(pairBuf, bbase, rowptr, deg, dinv, csr, N);

    const int nTiles = (N + 63) / 64;   // 1563
    const int gG = min(nTiles, 512);    // persistent grid-stride blocks
    gemm1_mfma<<<gG, 256, 0, stream>>>(x, W1t, dinv, H1, N, nTiles);
    agg1_fused<<<(N + 15) / 16, 256, 0, stream>>>(H1, csr, rowptr, deg, dinv, b1, W2t, H2, N);
    agg_lsm_64<<<(N + 15) / 16, 256, 0, stream>>>(H2, csr, rowptr, deg, dinv, b2, out, N);
}

// Round 7
// 250.543 us; speedup vs baseline: 1.0526x; 1.0526x over previous
//
#include <hip/hip_runtime.h>
#include <cstdint>
#include <cstddef>

#define IN_CH 128
#define HID_CH 128
#define OUT_CH 64
#define BSH 8        // nodes per bucket = 256
#define PB 4096      // edges per histogram/partition block

typedef unsigned int uint32;
typedef unsigned char uchar;
typedef short bf16x8 __attribute__((ext_vector_type(8)));
typedef float f32x4 __attribute__((ext_vector_type(4)));
typedef float f32x2 __attribute__((ext_vector_type(2)));

// float -> bf16 round-to-nearest-even
static __device__ __forceinline__ unsigned short f2bf(float f) {
    uint32 u = __float_as_uint(f);
    u += 0x7fffu + ((u >> 16) & 1u);
    return (unsigned short)(u >> 16);
}

// async global->LDS, 16B per lane, register-free (compiler cannot serialize)
typedef const __attribute__((address_space(1))) char gch;
typedef __attribute__((address_space(3))) char lch;
static __device__ __forceinline__ void gload16(const void* g, void* l) {
    __builtin_amdgcn_global_load_lds((gch*)g, (lch*)l, 16, 0, 0);
}

// ---------------- CSR build (bucketed, LDS-atomic only) ----------------

// bhist over buckets; wtrans fused into trailing blocks (independent work).
__global__ __launch_bounds__(256) void bhist_wtrans(
    const int* __restrict__ dst, int* __restrict__ bcnt, int E, int NB, int gP,
    const float* __restrict__ W1, const float* __restrict__ W2,
    unsigned short* __restrict__ W1t, unsigned short* __restrict__ W2t) {
    if (blockIdx.x >= (uint32)gP) {
        int t = (blockIdx.x - gP) * 256 + threadIdx.x;
        if (t < 128 * 128) {
            int nc = t >> 7, k = t & 127;
            W1t[t] = f2bf(W1[k * 128 + nc]);
        }
        int u = t - 128 * 128;
        if (u >= 0 && u < 64 * 128) {
            int nc = u >> 7, k = u & 127;
            W2t[u] = f2bf(W2[k * 64 + nc]);
        }
        return;
    }
    __shared__ int h[512];
    int t = threadIdx.x;
    int e0 = blockIdx.x * PB;
    int cnt = min(PB, E - e0);
    for (int b = t; b < NB; b += 256) h[b] = 0;
    __syncthreads();
    for (int i = t; i < cnt; i += 256)
        atomicAdd(&h[dst[e0 + i] >> BSH], 1);
    __syncthreads();
    for (int b = t; b < NB; b += 256)
        if (h[b]) atomicAdd(&bcnt[b], h[b]);
}

// cursors start at ZERO (part1 adds bbase[b] itself).
__global__ void bscan(const int* __restrict__ bcnt, int* __restrict__ bbase,
                      int* __restrict__ bcur, int NB, int E) {
    __shared__ int s[512];
    int t = threadIdx.x;
    int v = (t < NB) ? bcnt[t] : 0;
    s[t] = v;
    __syncthreads();
    for (int o = 1; o < 512; o <<= 1) {
        int add = (t >= o) ? s[t - o] : 0;
        __syncthreads();
        s[t] += add;
        __syncthreads();
    }
    if (t < NB) { bbase[t] = s[t] - v; bcur[t] = 0; }
    if (t == 0) bbase[NB] = E;
}

// part1: edges cached in LDS (single global read), histogram, then grouped write.
__global__ __launch_bounds__(256) void part1(
    const int* __restrict__ src, const int* __restrict__ dst,
    const int* __restrict__ bbase, int* __restrict__ bcur,
    int2* __restrict__ pairBuf, int E, int NB) {
    __shared__ int2 pairs[PB];          // 32 KB
    __shared__ int hist[512];
    __shared__ int base[512];
    int t = threadIdx.x;
    int e0 = blockIdx.x * PB;
    int cnt = min(PB, E - e0);
    for (int b = t; b < NB; b += 256) hist[b] = 0;
    __syncthreads();
    for (int i = t; i < cnt; i += 256) {
        int s = src[e0 + i], d = dst[e0 + i];
        pairs[i] = make_int2(s, d);
        atomicAdd(&hist[d >> BSH], 1);
    }
    __syncthreads();
    for (int b = t; b < NB; b += 256) {
        int h = hist[b];
        int gb = (h > 0) ? atomicAdd(&bcur[b], h) : 0;
        base[b] = bbase[b] + gb;
        hist[b] = 0;
    }
    __syncthreads();
    for (int i = t; i < cnt; i += 256) {
        int2 p = pairs[i];
        int b = p.y >> BSH;
        int q = base[b] + atomicAdd(&hist[b], 1);
        pairBuf[q] = p;
    }
}

__global__ __launch_bounds__(256) void bucket_build(
    const int2* __restrict__ pairBuf, const int* __restrict__ bbase,
    int* __restrict__ rowptr, int* __restrict__ deg, float* __restrict__ dinv,
    int* __restrict__ csr, int N) {
    __shared__ int cnt[256];
    __shared__ int loc[256];
    int b = blockIdx.x, t = threadIdx.x;
    int start = bbase[b], end = bbase[b + 1];
    cnt[t] = 0;
    __syncthreads();
    for (int i = start + t; i < end; i += 256)
        atomicAdd(&cnt[pairBuf[i].y & 255], 1);
    __syncthreads();
    int v = cnt[t];
    loc[t] = v;
    __syncthreads();
    for (int o = 1; o < 256; o <<= 1) {
        int add = (t >= o) ? loc[t - o] : 0;
        __syncthreads();
        loc[t] += add;
        __syncthreads();
    }
    int excl = loc[t] - v;
    int node = (b << BSH) + t;
    if (node < N) {
        rowptr[node] = start + excl;
        deg[node] = v;
        dinv[node] = rsqrtf((float)(v + 2));   // +2 self-loops
    }
    __syncthreads();
    cnt[t] = excl;                              // reuse as cursor
    __syncthreads();
    for (int i = start + t; i < end; i += 256) {
        int2 p = pairBuf[i];
        int q = start + atomicAdd(&cnt[p.y & 255], 1);
        csr[q] = p.x;
    }
}

// ---------------- MFMA GEMM1: H1[n,128] = fp8(dinv[n] * (x[n,128] @ W1)) ----------
// m97-style staging (global_load_lds width=16, register-free) + OPERAND-SWAPPED
// MFMA: acc[nt][p] holds 4 CONSECUTIVE channels of ONE node -> dword fp8 stores.

__global__ __launch_bounds__(256) void gemm1_mfma(
    const float* __restrict__ A, const unsigned short* __restrict__ Wt,
    const float* __restrict__ dinv, uchar* __restrict__ C, int n, int nTiles) {
    constexpr int NT = 8;                          // 128 out channels / 16
    __shared__ unsigned short Ws[128 * 136];       // padded W (34.8K)
    __shared__ char As[64 * 512];                  // 64-row fp32 tile (32K)

    const int t = threadIdx.x;

    // stage W once (padded pitch kills ds_read bank conflicts)
    for (int i = t; i < 128 * 16; i += 256) {
        int rr = i >> 4, sq = i & 15;
        *(uint4*)&Ws[rr * 136 + sq * 8] = *(const uint4*)(Wt + rr * 128 + sq * 8);
    }

    const int w = t >> 6, l = t & 63;
    const int q = l >> 4, r16 = l & 15;
    const int rw = w * 16 + r16;                   // this lane's node row in tile

    for (int tile = blockIdx.x; tile < nTiles; tile += gridDim.x) {
        const int row0 = tile * 64;

        // ---- stage A tile: linear LDS dest, per-lane clamped global source ----
#pragma unroll
        for (int rnd = 0; rnd < 8; rnd++) {
            int p = rnd * 4096 + t * 16;           // byte position in tile
            int row = row0 + (p >> 9);
            int col = p & 511;
            gload16((const char*)A + (size_t)min(row, n - 1) * 512 + col, As + p);
        }
        __syncthreads();   // drains vmcnt -> tile resident (and W on first iter)

        f32x4 acc[NT];
#pragma unroll
        for (int i = 0; i < NT; i++) acc[i] = (f32x4){0.f, 0.f, 0.f, 0.f};

#pragma unroll
        for (int s = 0; s < 4; s++) {
            const int k0 = s * 32 + q * 8;         // element k-offset
            // x-fragment (B operand: lane&15 -> node col)
            const float* Arow = (const float*)(As + rw * 512);
            float4 v0 = *(const float4*)(Arow + k0);
            float4 v1 = *(const float4*)(Arow + k0 + 4);
            bf16x8 xf;
            xf[0] = (short)f2bf(v0.x); xf[1] = (short)f2bf(v0.y);
            xf[2] = (short)f2bf(v0.z); xf[3] = (short)f2bf(v0.w);
            xf[4] = (short)f2bf(v1.x); xf[5] = (short)f2bf(v1.y);
            xf[6] = (short)f2bf(v1.z); xf[7] = (short)f2bf(v1.w);
#pragma unroll
            for (int nt = 0; nt < NT; nt++) {
                // W-fragment (A operand: lane&15 -> channel row)
                bf16x8 wf = *(const bf16x8*)&Ws[(nt * 16 + r16) * 136 + k0];
                acc[nt] = __builtin_amdgcn_mfma_f32_16x16x32_bf16(wf, xf, acc[nt], 0, 0, 0);
            }
        }

        // ---- epilogue: acc[nt][p] = channel (nt*16 + q*4 + p) of node rw ----
        const int node = row0 + rw;
        const bool nv = node < n;
        const float dv = dinv[min(node, n - 1)];
        uchar* Crow = C + (size_t)node * 128;
#pragma unroll
        for (int nt = 0; nt < NT; nt++) {
            int pk = 0;
            pk = __builtin_amdgcn_cvt_pk_fp8_f32(acc[nt][0] * dv, acc[nt][1] * dv, pk, false);
            pk = __builtin_amdgcn_cvt_pk_fp8_f32(acc[nt][2] * dv, acc[nt][3] * dv, pk, true);
            if (nv) *(uint32*)(Crow + nt * 16 + q * 4) = (uint32)pk;
        }
        __syncthreads();   // protect As from next tile's staging
    }
}

// ---------------- Fused agg1 + gemm2 (R5 structure + 16-deep full-batch path) ---
// 16-lane group per node, uint2 (8B) per lane per edge. Full 16-edge batches
// issue ALL 16 shuffles then ALL 16 gathers before accumulating -> 16 loads in
// flight/lane (was 8). Tails use the proven 8/4/1 paths. W2 MFMA fragments are
// loaded AFTER the barrier so they occupy no registers during the gather.

__global__ __launch_bounds__(256) void agg1_fused(
    const uchar* __restrict__ H, const int* __restrict__ csr,
    const int* __restrict__ rowptr, const int* __restrict__ deg,
    const float* __restrict__ dinv, const float* __restrict__ bias,
    const unsigned short* __restrict__ W2t, uchar* __restrict__ H2, int n) {
    __shared__ unsigned short tile[16 * 136];      // 16 nodes x 128ch bf16, padded
    int t = threadIdx.x;
    int g = t >> 4;                                 // node slot in block (0..15)
    int v = blockIdx.x * 16 + g;
    int hl = t & 15;
    int gsel = t & 48;
    bool valid = v < n;
    int vc = valid ? v : 0;
    int base = rowptr[vc];
    int cnt = valid ? deg[vc] : 0;
    const uint32 co = (uint32)(hl * 8);

    f32x2 A0 = (f32x2){0.f, 0.f}, A1 = A0, A2 = A0, A3 = A0;
    f32x2 B0 = A0, B1 = A0, B2 = A0, B3 = A0;

#define ACC128(h, s0, s1, s2, s3)                                   \
    {                                                               \
        s0 += __builtin_amdgcn_cvt_pk_f32_fp8((h).x, false);        \
        s1 += __builtin_amdgcn_cvt_pk_f32_fp8((h).x, true);         \
        s2 += __builtin_amdgcn_cvt_pk_f32_fp8((h).y, false);        \
        s3 += __builtin_amdgcn_cvt_pk_f32_fp8((h).y, true);         \
    }

    for (int j0 = 0; j0 < cnt; j0 += 16) {
        int nj = min(16, cnt - j0);
        int ul = 0;
        if (hl < nj) ul = csr[base + j0 + hl];
        if (nj == 16) {
            // full batch: 16 gathers in flight
            int u[16];
#pragma unroll
            for (int j = 0; j < 16; j++) u[j] = __shfl(ul, j | gsel);
            uint2 h[16];
#pragma unroll
            for (int j = 0; j < 16; j++)
                h[j] = *(const uint2*)(H + (((uint32)u[j] << 7) + co));
#pragma unroll
            for (int j = 0; j < 16; j += 2) {
                ACC128(h[j], A0, A1, A2, A3);
                ACC128(h[j + 1], B0, B1, B2, B3);
            }
        } else {
            int j = 0;
            for (; j + 8 <= nj; j += 8) {
                int u0 = __shfl(ul, (j + 0) | gsel), u1 = __shfl(ul, (j + 1) | gsel);
                int u2 = __shfl(ul, (j + 2) | gsel), u3 = __shfl(ul, (j + 3) | gsel);
                int u4 = __shfl(ul, (j + 4) | gsel), u5 = __shfl(ul, (j + 5) | gsel);
                int u6 = __shfl(ul, (j + 6) | gsel), u7 = __shfl(ul, (j + 7) | gsel);
                uint2 h0 = *(const uint2*)(H + (((uint32)u0 << 7) + co));
                uint2 h1 = *(const uint2*)(H + (((uint32)u1 << 7) + co));
                uint2 h2 = *(const uint2*)(H + (((uint32)u2 << 7) + co));
                uint2 h3 = *(const uint2*)(H + (((uint32)u3 << 7) + co));
                uint2 h4 = *(const uint2*)(H + (((uint32)u4 << 7) + co));
                uint2 h5 = *(const uint2*)(H + (((uint32)u5 << 7) + co));
                uint2 h6 = *(const uint2*)(H + (((uint32)u6 << 7) + co));
                uint2 h7 = *(const uint2*)(H + (((uint32)u7 << 7) + co));
                ACC128(h0, A0, A1, A2, A3);
                ACC128(h1, B0, B1, B2, B3);
                ACC128(h2, A0, A1, A2, A3);
                ACC128(h3, B0, B1, B2, B3);
                ACC128(h4, A0, A1, A2, A3);
                ACC128(h5, B0, B1, B2, B3);
                ACC128(h6, A0, A1, A2, A3);
                ACC128(h7, B0, B1, B2, B3);
            }
            for (; j + 4 <= nj; j += 4) {
                int u0 = __shfl(ul, (j + 0) | gsel), u1 = __shfl(ul, (j + 1) | gsel);
                int u2 = __shfl(ul, (j + 2) | gsel), u3 = __shfl(ul, (j + 3) | gsel);
                uint2 h0 = *(const uint2*)(H + (((uint32)u0 << 7) + co));
                uint2 h1 = *(const uint2*)(H + (((uint32)u1 << 7) + co));
                uint2 h2 = *(const uint2*)(H + (((uint32)u2 << 7) + co));
                uint2 h3 = *(const uint2*)(H + (((uint32)u3 << 7) + co));
                ACC128(h0, A0, A1, A2, A3);
                ACC128(h1, B0, B1, B2, B3);
                ACC128(h2, A0, A1, A2, A3);
                ACC128(h3, B0, B1, B2, B3);
            }
            for (; j < nj; j++) {
                int u = __shfl(ul, j | gsel);
                uint2 h = *(const uint2*)(H + (((uint32)u << 7) + co));
                ACC128(h, A0, A1, A2, A3);
            }
        }
    }
#undef ACC128

    // ---- finish hidden: self-loop + bias + ReLU, pack bf16 ----
    uint4 pk = make_uint4(0, 0, 0, 0);
    if (valid) {
        float dv = dinv[vc];
        uint2 hv = *(const uint2*)(H + (((uint32)vc << 7) + co));
        f32x2 s0 = __builtin_amdgcn_cvt_pk_f32_fp8(hv.x, false);
        f32x2 s1 = __builtin_amdgcn_cvt_pk_f32_fp8(hv.x, true);
        f32x2 s2 = __builtin_amdgcn_cvt_pk_f32_fp8(hv.y, false);
        f32x2 s3 = __builtin_amdgcn_cvt_pk_f32_fp8(hv.y, true);
        const f32x2* bp = (const f32x2*)(bias + hl * 8);
        f32x2 e0 = dv * ((A0 + B0) + 2.f * s0) + bp[0];
        f32x2 e1 = dv * ((A1 + B1) + 2.f * s1) + bp[1];
        f32x2 e2 = dv * ((A2 + B2) + 2.f * s2) + bp[2];
        f32x2 e3 = dv * ((A3 + B3) + 2.f * s3) + bp[3];
        float o0 = fmaxf(e0[0], 0.f), o1 = fmaxf(e0[1], 0.f);
        float o2 = fmaxf(e1[0], 0.f), o3 = fmaxf(e1[1], 0.f);
        float o4 = fmaxf(e2[0], 0.f), o5 = fmaxf(e2[1], 0.f);
        float o6 = fmaxf(e3[0], 0.f), o7 = fmaxf(e3[1], 0.f);
        pk.x = (uint32)f2bf(o0) | ((uint32)f2bf(o1) << 16);
        pk.y = (uint32)f2bf(o2) | ((uint32)f2bf(o3) << 16);
        pk.z = (uint32)f2bf(o4) | ((uint32)f2bf(o5) << 16);
        pk.w = (uint32)f2bf(o6) | ((uint32)f2bf(o7) << 16);
    }
    *(uint4*)&tile[g * 136 + hl * 8] = pk;
    __syncthreads();

    // ---- gemm2 tail: wave w -> channels w*16..+15 for all 16 nodes ----
    const int w = t >> 6, l = t & 63;
    const int q = l >> 4, r16 = l & 15;
    f32x4 acc2 = (f32x4){0.f, 0.f, 0.f, 0.f};
#pragma unroll
    for (int s = 0; s < 4; s++) {
        const int k0 = s * 32 + q * 8;
        bf16x8 hf = *(const bf16x8*)&tile[r16 * 136 + k0];                 // node r16
        bf16x8 wf = *(const bf16x8*)(W2t + (size_t)(w * 16 + r16) * 128 + k0); // channel
        acc2 = __builtin_amdgcn_mfma_f32_16x16x32_bf16(wf, hf, acc2, 0, 0, 0);
    }
    const int node = blockIdx.x * 16 + r16;
    if (node < n) {
        const float dv2 = dinv[node];
        int pk2 = 0;
        pk2 = __builtin_amdgcn_cvt_pk_fp8_f32(acc2[0] * dv2, acc2[1] * dv2, pk2, false);
        pk2 = __builtin_amdgcn_cvt_pk_fp8_f32(acc2[2] * dv2, acc2[3] * dv2, pk2, true);
        *(uint32*)(H2 + (size_t)node * 64 + w * 16 + q * 4) = (uint32)pk2;
    }
}

// agg2: 64 ch, lane covers 4 ch (uint = 4 fp8); 16-deep full-batch path;
// log_softmax within group of 16.
__global__ __launch_bounds__(256) void agg_lsm_64(
    const uchar* __restrict__ H, const int* __restrict__ csr,
    const int* __restrict__ rowptr, const int* __restrict__ deg,
    const float* __restrict__ dinv, const float* __restrict__ bias,
    float* __restrict__ out, int n) {
    int v = blockIdx.x * 16 + (threadIdx.x >> 4);
    int hl = threadIdx.x & 15;
    int gsel = threadIdx.x & 48;
    bool valid = v < n;
    int vc = valid ? v : 0;
    int base = rowptr[vc];
    int cnt = valid ? deg[vc] : 0;
    const uint32 co = (uint32)(hl * 4);

    f32x2 A0 = (f32x2){0.f, 0.f}, A1 = A0, B0 = A0, B1 = A0;

#define ACC64(h, s0, s1)                                            \
    {                                                               \
        s0 += __builtin_amdgcn_cvt_pk_f32_fp8((h), false);          \
        s1 += __builtin_amdgcn_cvt_pk_f32_fp8((h), true);           \
    }

    for (int j0 = 0; j0 < cnt; j0 += 16) {
        int nj = min(16, cnt - j0);
        int ul = 0;
        if (hl < nj) ul = csr[base + j0 + hl];
        if (nj == 16) {
            int u[16];
#pragma unroll
            for (int j = 0; j < 16; j++) u[j] = __shfl(ul, j | gsel);
            uint32 h[16];
#pragma unroll
            for (int j = 0; j < 16; j++)
                h[j] = *(const uint32*)(H + (((uint32)u[j] << 6) + co));
#pragma unroll
            for (int j = 0; j < 16; j += 2) {
                ACC64(h[j], A0, A1);
                ACC64(h[j + 1], B0, B1);
            }
        } else {
            int j = 0;
            for (; j + 8 <= nj; j += 8) {
                int u0 = __shfl(ul, (j + 0) | gsel), u1 = __shfl(ul, (j + 1) | gsel);
                int u2 = __shfl(ul, (j + 2) | gsel), u3 = __shfl(ul, (j + 3) | gsel);
                int u4 = __shfl(ul, (j + 4) | gsel), u5 = __shfl(ul, (j + 5) | gsel);
                int u6 = __shfl(ul, (j + 6) | gsel), u7 = __shfl(ul, (j + 7) | gsel);
                uint32 h0 = *(const uint32*)(H + (((uint32)u0 << 6) + co));
                uint32 h1 = *(const uint32*)(H + (((uint32)u1 << 6) + co));
                uint32 h2 = *(const uint32*)(H + (((uint32)u2 << 6) + co));
                uint32 h3 = *(const uint32*)(H + (((uint32)u3 << 6) + co));
                uint32 h4 = *(const uint32*)(H + (((uint32)u4 << 6) + co));
                uint32 h5 = *(const uint32*)(H + (((uint32)u5 << 6) + co));
                uint32 h6 = *(const uint32*)(H + (((uint32)u6 << 6) + co));
                uint32 h7 = *(const uint32*)(H + (((uint32)u7 << 6) + co));
                ACC64(h0, A0, A1);
                ACC64(h1, B0, B1);
                ACC64(h2, A0, A1);
                ACC64(h3, B0, B1);
                ACC64(h4, A0, A1);
                ACC64(h5, B0, B1);
                ACC64(h6, A0, A1);
                ACC64(h7, B0, B1);
            }
            for (; j + 4 <= nj; j += 4) {
                int u0 = __shfl(ul, (j + 0) | gsel), u1 = __shfl(ul, (j + 1) | gsel);
                int u2 = __shfl(ul, (j + 2) | gsel), u3 = __shfl(ul, (j + 3) | gsel);
                uint32 h0 = *(const uint32*)(H + (((uint32)u0 << 6) + co));
                uint32 h1 = *(const uint32*)(H + (((uint32)u1 << 6) + co));
                uint32 h2 = *(const uint32*)(H + (((uint32)u2 << 6) + co));
                uint32 h3 = *(const uint32*)(H + (((uint32)u3 << 6) + co));
                ACC64(h0, A0, A1);
                ACC64(h1, B0, B1);
                ACC64(h2, A0, A1);
                ACC64(h3, B0, B1);
            }
            for (; j < nj; j++) {
                int u = __shfl(ul, j | gsel);
                uint32 h = *(const uint32*)(H + (((uint32)u << 6) + co));
                ACC64(h, A0, A1);
            }
        }
    }
#undef ACC64

    float dv = dinv[vc];
    uint32 hv = *(const uint32*)(H + (((uint32)vc << 6) + co));
    f32x2 s0 = __builtin_amdgcn_cvt_pk_f32_fp8(hv, false);
    f32x2 s1 = __builtin_amdgcn_cvt_pk_f32_fp8(hv, true);
    const f32x2* bp = (const f32x2*)(bias + hl * 4);
    f32x2 w0 = dv * ((A0 + B0) + 2.f * s0) + bp[0];
    f32x2 w1 = dv * ((A1 + B1) + 2.f * s1) + bp[1];
    float v0 = w0[0], v1 = w0[1], v2 = w1[0], v3 = w1[1];
    // log_softmax across the 64 channels held by this 16-lane group
    float m = fmaxf(fmaxf(v0, v1), fmaxf(v2, v3));
    for (int o = 8; o > 0; o >>= 1) m = fmaxf(m, __shfl_xor(m, o));
    float e = (__expf(v0 - m) + __expf(v1 - m)) + (__expf(v2 - m) + __expf(v3 - m));
    for (int o = 8; o > 0; o >>= 1) e += __shfl_xor(e, o);
    float ls = m + __logf(e);
    if (valid)
        *(float4*)(out + (size_t)vc * 64 + hl * 4) =
            make_float4(v0 - ls, v1 - ls, v2 - ls, v3 - ls);
}

// ---------------- launch ----------------

extern "C" void kernel_launch(void* const* d_in, const int* in_sizes, int n_in,
                              void* d_out, int out_size, void* d_ws, size_t ws_size,
                              hipStream_t stream) {
    const float* x  = (const float*)d_in[0];
    const int*   ei = (const int*)d_in[1];
    const float* W1 = (const float*)d_in[2];
    const float* b1 = (const float*)d_in[3];
    const float* W2 = (const float*)d_in[4];
    const float* b2 = (const float*)d_in[5];
    float* out = (float*)d_out;

    const int N = in_sizes[0] / IN_CH;  // 100000
    const int E = in_sizes[1] / 2;      // 1600000
    const int* src = ei;
    const int* dst = ei + E;
    const int NB = (N + 255) >> BSH;    // 391 buckets

    char* w = (char*)d_ws;
    size_t off = 0;
    auto alloc = [&](size_t bytes) -> char* {
        char* p = w + off;
        off = (off + bytes + 255) & ~(size_t)255;
        return p;
    };
    int*   deg    = (int*)alloc((size_t)N * 4);
    int*   rowptr = (int*)alloc((size_t)N * 4);
    int*   bcnt   = (int*)alloc(512 * 4);
    int*   bbase  = (int*)alloc(513 * 4);
    int*   bcur   = (int*)alloc(512 * 4);
    float* dinv   = (float*)alloc((size_t)N * 4 + 1024);  // +pad for vector tails
    int*   csr    = (int*)alloc((size_t)E * 4);
    unsigned short* W1t = (unsigned short*)alloc(128 * 128 * 2);
    unsigned short* W2t = (unsigned short*)alloc(64 * 128 * 2);
    uchar* H1  = (uchar*)alloc((size_t)N * HID_CH);          // fp8, 12.8 MB
    char*  scratch = alloc((size_t)E * 8);                   // pairBuf then H2
    uchar* H2  = (uchar*)scratch;        // fp8, 6.4 MB (pairBuf dead after bucket_build)
    int2*  pairBuf = (int2*)scratch;

    hipMemsetAsync(bcnt, 0, 512 * 4, stream);

    int gP = (E + PB - 1) / PB;         // 391 partition blocks

    bhist_wtrans<<<gP + 96, 256, 0, stream>>>(dst, bcnt, E, NB, gP, W1, W2, W1t, W2t);
    bscan<<<1, 512, 0, stream>>>(bcnt, bbase, bcur, NB, E);
    part1<<<gP, 256, 0, stream>>>(src, dst, bbase, bcur, pairBuf, E, NB);
    bucket_build<<<NB, 256, 0, stream>>>(pairBuf, bbase, rowptr, deg, dinv, csr, N);

    const int nTiles = (N + 63) / 64;   // 1563
    const int gG = min(nTiles, 512);    // persistent grid-stride blocks
    gemm1_mfma<<<gG, 256, 0, stream>>>(x, W1t, dinv, H1, N, nTiles);
    agg1_fused<<<(N + 15) / 16, 256, 0, stream>>>(H1, csr, rowptr, deg, dinv, b1, W2t, H2, N);
    agg_lsm_64<<<(N + 15) / 16, 256, 0, stream>>>(H2, csr, rowptr, deg, dinv, b2, out, N);
}

// Round 8
// 234.010 us; speedup vs baseline: 1.1270x; 1.0707x over previous
//
#include <hip/hip_runtime.h>
#include <cstdint>
#include <cstddef>

#define IN_CH 128
#define HID_CH 128
#define OUT_CH 64
#define BSH 8        // nodes per bucket = 256
#define PB 4096      // edges per histogram/partition block

typedef unsigned int uint32;
typedef unsigned char uchar;
typedef short bf16x8 __attribute__((ext_vector_type(8)));
typedef float f32x4 __attribute__((ext_vector_type(4)));
typedef float f32x2 __attribute__((ext_vector_type(2)));

// float -> bf16 round-to-nearest-even
static __device__ __forceinline__ unsigned short f2bf(float f) {
    uint32 u = __float_as_uint(f);
    u += 0x7fffu + ((u >> 16) & 1u);
    return (unsigned short)(u >> 16);
}

// async global->LDS, 16B per lane, register-free (compiler cannot serialize).
// Global source address is PER-LANE; LDS dest is wave-uniform base + lane*16.
typedef const __attribute__((address_space(1))) char gch;
typedef __attribute__((address_space(3))) char lch;
static __device__ __forceinline__ void gload16(const void* g, void* l) {
    __builtin_amdgcn_global_load_lds((gch*)g, (lch*)l, 16, 0, 0);
}

// ---------------- CSR build (bucketed, LDS-atomic only) ----------------

// bhist over buckets; wtrans fused into trailing blocks (independent work).
__global__ __launch_bounds__(256) void bhist_wtrans(
    const int* __restrict__ dst, int* __restrict__ bcnt, int E, int NB, int gP,
    const float* __restrict__ W1, const float* __restrict__ W2,
    unsigned short* __restrict__ W1t, unsigned short* __restrict__ W2t) {
    if (blockIdx.x >= (uint32)gP) {
        int t = (blockIdx.x - gP) * 256 + threadIdx.x;
        if (t < 128 * 128) {
            int nc = t >> 7, k = t & 127;
            W1t[t] = f2bf(W1[k * 128 + nc]);
        }
        int u = t - 128 * 128;
        if (u >= 0 && u < 64 * 128) {
            int nc = u >> 7, k = u & 127;
            W2t[u] = f2bf(W2[k * 64 + nc]);
        }
        return;
    }
    __shared__ int h[512];
    int t = threadIdx.x;
    int e0 = blockIdx.x * PB;
    int cnt = min(PB, E - e0);
    for (int b = t; b < NB; b += 256) h[b] = 0;
    __syncthreads();
    for (int i = t; i < cnt; i += 256)
        atomicAdd(&h[dst[e0 + i] >> BSH], 1);
    __syncthreads();
    for (int b = t; b < NB; b += 256)
        if (h[b]) atomicAdd(&bcnt[b], h[b]);
}

// cursors start at ZERO (part1 adds bbase[b] itself).
__global__ void bscan(const int* __restrict__ bcnt, int* __restrict__ bbase,
                      int* __restrict__ bcur, int NB, int E) {
    __shared__ int s[512];
    int t = threadIdx.x;
    int v = (t < NB) ? bcnt[t] : 0;
    s[t] = v;
    __syncthreads();
    for (int o = 1; o < 512; o <<= 1) {
        int add = (t >= o) ? s[t - o] : 0;
        __syncthreads();
        s[t] += add;
        __syncthreads();
    }
    if (t < NB) { bbase[t] = s[t] - v; bcur[t] = 0; }
    if (t == 0) bbase[NB] = E;
}

// part1: edges cached in LDS (single global read), histogram, then grouped write.
__global__ __launch_bounds__(256) void part1(
    const int* __restrict__ src, const int* __restrict__ dst,
    const int* __restrict__ bbase, int* __restrict__ bcur,
    int2* __restrict__ pairBuf, int E, int NB) {
    __shared__ int2 pairs[PB];          // 32 KB
    __shared__ int hist[512];
    __shared__ int base[512];
    int t = threadIdx.x;
    int e0 = blockIdx.x * PB;
    int cnt = min(PB, E - e0);
    for (int b = t; b < NB; b += 256) hist[b] = 0;
    __syncthreads();
    for (int i = t; i < cnt; i += 256) {
        int s = src[e0 + i], d = dst[e0 + i];
        pairs[i] = make_int2(s, d);
        atomicAdd(&hist[d >> BSH], 1);
    }
    __syncthreads();
    for (int b = t; b < NB; b += 256) {
        int h = hist[b];
        int gb = (h > 0) ? atomicAdd(&bcur[b], h) : 0;
        base[b] = bbase[b] + gb;
        hist[b] = 0;
    }
    __syncthreads();
    for (int i = t; i < cnt; i += 256) {
        int2 p = pairs[i];
        int b = p.y >> BSH;
        int q = base[b] + atomicAdd(&hist[b], 1);
        pairBuf[q] = p;
    }
}

__global__ __launch_bounds__(256) void bucket_build(
    const int2* __restrict__ pairBuf, const int* __restrict__ bbase,
    int* __restrict__ rowptr, int* __restrict__ deg, float* __restrict__ dinv,
    int* __restrict__ csr, int N) {
    __shared__ int cnt[256];
    __shared__ int loc[256];
    int b = blockIdx.x, t = threadIdx.x;
    int start = bbase[b], end = bbase[b + 1];
    cnt[t] = 0;
    __syncthreads();
    for (int i = start + t; i < end; i += 256)
        atomicAdd(&cnt[pairBuf[i].y & 255], 1);
    __syncthreads();
    int v = cnt[t];
    loc[t] = v;
    __syncthreads();
    for (int o = 1; o < 256; o <<= 1) {
        int add = (t >= o) ? loc[t - o] : 0;
        __syncthreads();
        loc[t] += add;
        __syncthreads();
    }
    int excl = loc[t] - v;
    int node = (b << BSH) + t;
    if (node < N) {
        rowptr[node] = start + excl;
        deg[node] = v;
        dinv[node] = rsqrtf((float)(v + 2));   // +2 self-loops
    }
    __syncthreads();
    cnt[t] = excl;                              // reuse as cursor
    __syncthreads();
    for (int i = start + t; i < end; i += 256) {
        int2 p = pairBuf[i];
        int q = start + atomicAdd(&cnt[p.y & 255], 1);
        csr[q] = p.x;
    }
}

// ---------------- MFMA GEMM1: H1[n,128] = fp8(dinv[n] * (x[n,128] @ W1)) ----------
// m97-style staging (global_load_lds width=16, register-free) + OPERAND-SWAPPED
// MFMA: acc[nt][p] holds 4 CONSECUTIVE channels of ONE node -> dword fp8 stores.

__global__ __launch_bounds__(256) void gemm1_mfma(
    const float* __restrict__ A, const unsigned short* __restrict__ Wt,
    const float* __restrict__ dinv, uchar* __restrict__ C, int n, int nTiles) {
    constexpr int NT = 8;                          // 128 out channels / 16
    __shared__ unsigned short Ws[128 * 136];       // padded W (34.8K)
    __shared__ char As[64 * 512];                  // 64-row fp32 tile (32K)

    const int t = threadIdx.x;

    // stage W once (padded pitch kills ds_read bank conflicts)
    for (int i = t; i < 128 * 16; i += 256) {
        int rr = i >> 4, sq = i & 15;
        *(uint4*)&Ws[rr * 136 + sq * 8] = *(const uint4*)(Wt + rr * 128 + sq * 8);
    }

    const int w = t >> 6, l = t & 63;
    const int q = l >> 4, r16 = l & 15;
    const int rw = w * 16 + r16;                   // this lane's node row in tile

    for (int tile = blockIdx.x; tile < nTiles; tile += gridDim.x) {
        const int row0 = tile * 64;

        // ---- stage A tile: linear LDS dest, per-lane clamped global source ----
#pragma unroll
        for (int rnd = 0; rnd < 8; rnd++) {
            int p = rnd * 4096 + t * 16;           // byte position in tile
            int row = row0 + (p >> 9);
            int col = p & 511;
            gload16((const char*)A + (size_t)min(row, n - 1) * 512 + col, As + p);
        }
        __syncthreads();   // drains vmcnt -> tile resident (and W on first iter)

        f32x4 acc[NT];
#pragma unroll
        for (int i = 0; i < NT; i++) acc[i] = (f32x4){0.f, 0.f, 0.f, 0.f};

#pragma unroll
        for (int s = 0; s < 4; s++) {
            const int k0 = s * 32 + q * 8;         // element k-offset
            // x-fragment (B operand: lane&15 -> node col)
            const float* Arow = (const float*)(As + rw * 512);
            float4 v0 = *(const float4*)(Arow + k0);
            float4 v1 = *(const float4*)(Arow + k0 + 4);
            bf16x8 xf;
            xf[0] = (short)f2bf(v0.x); xf[1] = (short)f2bf(v0.y);
            xf[2] = (short)f2bf(v0.z); xf[3] = (short)f2bf(v0.w);
            xf[4] = (short)f2bf(v1.x); xf[5] = (short)f2bf(v1.y);
            xf[6] = (short)f2bf(v1.z); xf[7] = (short)f2bf(v1.w);
#pragma unroll
            for (int nt = 0; nt < NT; nt++) {
                // W-fragment (A operand: lane&15 -> channel row)
                bf16x8 wf = *(const bf16x8*)&Ws[(nt * 16 + r16) * 136 + k0];
                acc[nt] = __builtin_amdgcn_mfma_f32_16x16x32_bf16(wf, xf, acc[nt], 0, 0, 0);
            }
        }

        // ---- epilogue: acc[nt][p] = channel (nt*16 + q*4 + p) of node rw ----
        const int node = row0 + rw;
        const bool nv = node < n;
        const float dv = dinv[min(node, n - 1)];
        uchar* Crow = C + (size_t)node * 128;
#pragma unroll
        for (int nt = 0; nt < NT; nt++) {
            int pk = 0;
            pk = __builtin_amdgcn_cvt_pk_fp8_f32(acc[nt][0] * dv, acc[nt][1] * dv, pk, false);
            pk = __builtin_amdgcn_cvt_pk_fp8_f32(acc[nt][2] * dv, acc[nt][3] * dv, pk, true);
            if (nv) *(uint32*)(Crow + nt * 16 + q * 4) = (uint32)pk;
        }
        __syncthreads();   // protect As from next tile's staging
    }
}

// ---------------- Fused agg1 + gemm2: LDS-staged gather ------------------------
// Per 16-edge batch, each WAVE stages its 4 groups x 16 rows x 128 B (8 KB) into
// a private LDS slice via 8x global_load_lds (per-lane GLOBAL addresses, linear
// LDS dest, ZERO VGPR cost -> 8 KB in flight per wave, un-serializable), then
// one vmcnt(0) and consume from LDS. Chunk c of edge j (group g) lives at
// slice[(j>>1)*1024 + g*256 + (j&1)*128 + c*16].

__global__ __launch_bounds__(256) void agg1_fused(
    const uchar* __restrict__ H, const int* __restrict__ csr,
    const int* __restrict__ rowptr, const int* __restrict__ deg,
    const float* __restrict__ dinv, const float* __restrict__ bias,
    const unsigned short* __restrict__ W2t, uchar* __restrict__ H2, int n) {
    __shared__ char stage[4][8192];                // per-wave gather slices
    __shared__ unsigned short tile[16 * 136];      // 16 nodes x 128ch bf16, padded
    int t = threadIdx.x;
    int slot = t >> 4;                              // node slot in block (0..15)
    int v = blockIdx.x * 16 + slot;
    int hl = t & 15;
    int gsel = t & 48;
    int w = t >> 6;                                 // wave id
    int gg = (t >> 4) & 3;                          // group within wave
    bool valid = v < n;
    int vc = valid ? v : 0;
    int base = rowptr[vc];
    int cnt = valid ? deg[vc] : 0;

    f32x2 A0 = (f32x2){0.f, 0.f}, A1 = A0, A2 = A0, A3 = A0;
    f32x2 B0 = A0, B1 = A0, B2 = A0, B3 = A0;

#define ACC128(h, s0, s1, s2, s3)                                   \
    {                                                               \
        s0 += __builtin_amdgcn_cvt_pk_f32_fp8((h).x, false);        \
        s1 += __builtin_amdgcn_cvt_pk_f32_fp8((h).x, true);         \
        s2 += __builtin_amdgcn_cvt_pk_f32_fp8((h).y, false);        \
        s3 += __builtin_amdgcn_cvt_pk_f32_fp8((h).y, true);         \
    }

    char* sl = stage[w];
    const char* rg = sl + gg * 256 + hl * 8;       // consume base for this lane

    for (int j0 = 0; j0 < cnt; j0 += 16) {
        int nj = min(16, cnt - j0);
        int ul = 0;
        if (hl < nj) ul = csr[base + j0 + hl];     // garbage lanes -> row 0
        // ---- issue: 8x global_load_lds, 8 KB in flight, no VGPR held ----
#pragma unroll
        for (int i = 0; i < 8; i++) {
            int j = i * 2 + (hl >> 3);
            int u = __shfl(ul, j | gsel);
            gload16(H + (((uint32)u << 7) + ((uint32)(hl & 7) << 4)),
                    sl + i * 1024);
        }
        asm volatile("s_waitcnt vmcnt(0)" ::: "memory");
        __builtin_amdgcn_sched_barrier(0);
        // ---- consume from LDS (predicated on per-group edge count) ----
#pragma unroll
        for (int j = 0; j < 16; j++) {
            if (j < nj) {
                uint2 h = *(const uint2*)(rg + (j >> 1) * 1024 + (j & 1) * 128);
                if (j & 1) { ACC128(h, B0, B1, B2, B3); }
                else       { ACC128(h, A0, A1, A2, A3); }
            }
        }
    }
#undef ACC128

    // ---- finish hidden: self-loop + bias + ReLU, pack bf16 ----
    const uint32 co = (uint32)(hl * 8);
    uint4 pk = make_uint4(0, 0, 0, 0);
    if (valid) {
        float dv = dinv[vc];
        uint2 hv = *(const uint2*)(H + (((uint32)vc << 7) + co));
        f32x2 s0 = __builtin_amdgcn_cvt_pk_f32_fp8(hv.x, false);
        f32x2 s1 = __builtin_amdgcn_cvt_pk_f32_fp8(hv.x, true);
        f32x2 s2 = __builtin_amdgcn_cvt_pk_f32_fp8(hv.y, false);
        f32x2 s3 = __builtin_amdgcn_cvt_pk_f32_fp8(hv.y, true);
        const f32x2* bp = (const f32x2*)(bias + hl * 8);
        f32x2 e0 = dv * ((A0 + B0) + 2.f * s0) + bp[0];
        f32x2 e1 = dv * ((A1 + B1) + 2.f * s1) + bp[1];
        f32x2 e2 = dv * ((A2 + B2) + 2.f * s2) + bp[2];
        f32x2 e3 = dv * ((A3 + B3) + 2.f * s3) + bp[3];
        float o0 = fmaxf(e0[0], 0.f), o1 = fmaxf(e0[1], 0.f);
        float o2 = fmaxf(e1[0], 0.f), o3 = fmaxf(e1[1], 0.f);
        float o4 = fmaxf(e2[0], 0.f), o5 = fmaxf(e2[1], 0.f);
        float o6 = fmaxf(e3[0], 0.f), o7 = fmaxf(e3[1], 0.f);
        pk.x = (uint32)f2bf(o0) | ((uint32)f2bf(o1) << 16);
        pk.y = (uint32)f2bf(o2) | ((uint32)f2bf(o3) << 16);
        pk.z = (uint32)f2bf(o4) | ((uint32)f2bf(o5) << 16);
        pk.w = (uint32)f2bf(o6) | ((uint32)f2bf(o7) << 16);
    }
    *(uint4*)&tile[slot * 136 + hl * 8] = pk;
    __syncthreads();

    // ---- gemm2 tail: wave w -> channels w*16..+15 for all 16 nodes ----
    const int l = t & 63;
    const int q = l >> 4, r16 = l & 15;
    f32x4 acc2 = (f32x4){0.f, 0.f, 0.f, 0.f};
#pragma unroll
    for (int s = 0; s < 4; s++) {
        const int k0 = s * 32 + q * 8;
        bf16x8 hf = *(const bf16x8*)&tile[r16 * 136 + k0];                 // node r16
        bf16x8 wf = *(const bf16x8*)(W2t + (size_t)(w * 16 + r16) * 128 + k0); // channel
        acc2 = __builtin_amdgcn_mfma_f32_16x16x32_bf16(wf, hf, acc2, 0, 0, 0);
    }
    const int node = blockIdx.x * 16 + r16;
    if (node < n) {
        const float dv2 = dinv[node];
        int pk2 = 0;
        pk2 = __builtin_amdgcn_cvt_pk_fp8_f32(acc2[0] * dv2, acc2[1] * dv2, pk2, false);
        pk2 = __builtin_amdgcn_cvt_pk_fp8_f32(acc2[2] * dv2, acc2[3] * dv2, pk2, true);
        *(uint32*)(H2 + (size_t)node * 64 + w * 16 + q * 4) = (uint32)pk2;
    }
}

// agg2: 64 ch; same LDS-staged gather (4 instrs/batch, 4 KB/wave in flight).
// Chunk c of edge j (group g): slice[(j>>2)*1024 + g*256 + (j&3)*64 + c*16].
// log_softmax within group of 16.
__global__ __launch_bounds__(256) void agg_lsm_64(
    const uchar* __restrict__ H, const int* __restrict__ csr,
    const int* __restrict__ rowptr, const int* __restrict__ deg,
    const float* __restrict__ dinv, const float* __restrict__ bias,
    float* __restrict__ out, int n) {
    __shared__ char stage[4][4096];
    int t = threadIdx.x;
    int v = blockIdx.x * 16 + (t >> 4);
    int hl = t & 15;
    int gsel = t & 48;
    int w = t >> 6;
    int gg = (t >> 4) & 3;
    bool valid = v < n;
    int vc = valid ? v : 0;
    int base = rowptr[vc];
    int cnt = valid ? deg[vc] : 0;
    const uint32 co = (uint32)(hl * 4);

    f32x2 A0 = (f32x2){0.f, 0.f}, A1 = A0, B0 = A0, B1 = A0;

#define ACC64(h, s0, s1)                                            \
    {                                                               \
        s0 += __builtin_amdgcn_cvt_pk_f32_fp8((h), false);          \
        s1 += __builtin_amdgcn_cvt_pk_f32_fp8((h), true);           \
    }

    char* sl = stage[w];
    const char* rg = sl + gg * 256 + hl * 4;

    for (int j0 = 0; j0 < cnt; j0 += 16) {
        int nj = min(16, cnt - j0);
        int ul = 0;
        if (hl < nj) ul = csr[base + j0 + hl];
#pragma unroll
        for (int i = 0; i < 4; i++) {
            int j = i * 4 + (hl >> 2);
            int u = __shfl(ul, j | gsel);
            gload16(H + (((uint32)u << 6) + ((uint32)(hl & 3) << 4)),
                    sl + i * 1024);
        }
        asm volatile("s_waitcnt vmcnt(0)" ::: "memory");
        __builtin_amdgcn_sched_barrier(0);
#pragma unroll
        for (int j = 0; j < 16; j++) {
            if (j < nj) {
                uint32 h = *(const uint32*)(rg + (j >> 2) * 1024 + (j & 3) * 64);
                if (j & 1) { ACC64(h, B0, B1); }
                else       { ACC64(h, A0, A1); }
            }
        }
    }
#undef ACC64

    float dv = dinv[vc];
    uint32 hv = *(const uint32*)(H + (((uint32)vc << 6) + co));
    f32x2 s0 = __builtin_amdgcn_cvt_pk_f32_fp8(hv, false);
    f32x2 s1 = __builtin_amdgcn_cvt_pk_f32_fp8(hv, true);
    const f32x2* bp = (const f32x2*)(bias + hl * 4);
    f32x2 w0 = dv * ((A0 + B0) + 2.f * s0) + bp[0];
    f32x2 w1 = dv * ((A1 + B1) + 2.f * s1) + bp[1];
    float v0 = w0[0], v1 = w0[1], v2 = w1[0], v3 = w1[1];
    // log_softmax across the 64 channels held by this 16-lane group
    float m = fmaxf(fmaxf(v0, v1), fmaxf(v2, v3));
    for (int o = 8; o > 0; o >>= 1) m = fmaxf(m, __shfl_xor(m, o));
    float e = (__expf(v0 - m) + __expf(v1 - m)) + (__expf(v2 - m) + __expf(v3 - m));
    for (int o = 8; o > 0; o >>= 1) e += __shfl_xor(e, o);
    float ls = m + __logf(e);
    if (valid)
        *(float4*)(out + (size_t)vc * 64 + hl * 4) =
            make_float4(v0 - ls, v1 - ls, v2 - ls, v3 - ls);
}

// ---------------- launch ----------------

extern "C" void kernel_launch(void* const* d_in, const int* in_sizes, int n_in,
                              void* d_out, int out_size, void* d_ws, size_t ws_size,
                              hipStream_t stream) {
    const float* x  = (const float*)d_in[0];
    const int*   ei = (const int*)d_in[1];
    const float* W1 = (const float*)d_in[2];
    const float* b1 = (const float*)d_in[3];
    const float* W2 = (const float*)d_in[4];
    const float* b2 = (const float*)d_in[5];
    float* out = (float*)d_out;

    const int N = in_sizes[0] / IN_CH;  // 100000
    const int E = in_sizes[1] / 2;      // 1600000
    const int* src = ei;
    const int* dst = ei + E;
    const int NB = (N + 255) >> BSH;    // 391 buckets

    char* w = (char*)d_ws;
    size_t off = 0;
    auto alloc = [&](size_t bytes) -> char* {
        char* p = w + off;
        off = (off + bytes + 255) & ~(size_t)255;
        return p;
    };
    int*   deg    = (int*)alloc((size_t)N * 4);
    int*   rowptr = (int*)alloc((size_t)N * 4);
    int*   bcnt   = (int*)alloc(512 * 4);
    int*   bbase  = (int*)alloc(513 * 4);
    int*   bcur   = (int*)alloc(512 * 4);
    float* dinv   = (float*)alloc((size_t)N * 4 + 1024);  // +pad for vector tails
    int*   csr    = (int*)alloc((size_t)E * 4);
    unsigned short* W1t = (unsigned short*)alloc(128 * 128 * 2);
    unsigned short* W2t = (unsigned short*)alloc(64 * 128 * 2);
    uchar* H1  = (uchar*)alloc((size_t)N * HID_CH);          // fp8, 12.8 MB
    char*  scratch = alloc((size_t)E * 8);                   // pairBuf then H2
    uchar* H2  = (uchar*)scratch;        // fp8, 6.4 MB (pairBuf dead after bucket_build)
    int2*  pairBuf = (int2*)scratch;

    hipMemsetAsync(bcnt, 0, 512 * 4, stream);

    int gP = (E + PB - 1) / PB;         // 391 partition blocks

    bhist_wtrans<<<gP + 96, 256, 0, stream>>>(dst, bcnt, E, NB, gP, W1, W2, W1t, W2t);
    bscan<<<1, 512, 0, stream>>>(bcnt, bbase, bcur, NB, E);
    part1<<<gP, 256, 0, stream>>>(src, dst, bbase, bcur, pairBuf, E, NB);
    bucket_build<<<NB, 256, 0, stream>>>(pairBuf, bbase, rowptr, deg, dinv, csr, N);

    const int nTiles = (N + 63) / 64;   // 1563
    const int gG = min(nTiles, 512);    // persistent grid-stride blocks
    gemm1_mfma<<<gG, 256, 0, stream>>>(x, W1t, dinv, H1, N, nTiles);
    agg1_fused<<<(N + 15) / 16, 256, 0, stream>>>(H1, csr, rowptr, deg, dinv, b1, W2t, H2, N);
    agg_lsm_64<<<(N + 15) / 16, 256, 0, stream>>>(H2, csr, rowptr, deg, dinv, b2, out, N);
}

// Round 9
// 217.189 us; speedup vs baseline: 1.2142x; 1.0774x over previous
//
#include <hip/hip_runtime.h>
#include <cstdint>
#include <cstddef>

#define IN_CH 128
#define HID_CH 128
#define OUT_CH 64
#define BSH 8        // nodes per bucket = 256
#define PB 4096      // edges per partition block
#define CAP 6144     // bucket segment capacity (mean 4092, +32 sigma)

typedef unsigned int uint32;
typedef unsigned char uchar;
typedef short bf16x8 __attribute__((ext_vector_type(8)));
typedef float f32x4 __attribute__((ext_vector_type(4)));
typedef float f32x2 __attribute__((ext_vector_type(2)));

// float -> bf16 round-to-nearest-even
static __device__ __forceinline__ unsigned short f2bf(float f) {
    uint32 u = __float_as_uint(f);
    u += 0x7fffu + ((u >> 16) & 1u);
    return (unsigned short)(u >> 16);
}

// async global->LDS, 16B per lane, register-free (compiler cannot serialize).
// Global source address is PER-LANE; LDS dest is wave-uniform base + lane*16.
typedef const __attribute__((address_space(1))) char gch;
typedef __attribute__((address_space(3))) char lch;
static __device__ __forceinline__ void gload16(const void* g, void* l) {
    __builtin_amdgcn_global_load_lds((gch*)g, (lch*)l, 16, 0, 0);
}

// ---------------- CSR build: single-pass segmented buckets ----------------
// part1_wtrans: per-block LDS histogram -> one atomicAdd per touched bucket
// claims space in the bucket's FIXED segment (b*CAP) -> grouped scatter.
// No global pre-histogram, no scan. W transpose fused into trailing blocks.

__global__ __launch_bounds__(256) void part1_wtrans(
    const int* __restrict__ src, const int* __restrict__ dst,
    int* __restrict__ bcur, int2* __restrict__ pairBuf, int E, int NB, int gP,
    const float* __restrict__ W1, const float* __restrict__ W2,
    unsigned short* __restrict__ W1t, unsigned short* __restrict__ W2t) {
    if (blockIdx.x >= (uint32)gP) {
        int t = (blockIdx.x - gP) * 256 + threadIdx.x;
        if (t < 128 * 128) {
            int nc = t >> 7, k = t & 127;
            W1t[t] = f2bf(W1[k * 128 + nc]);
        }
        int u = t - 128 * 128;
        if (u >= 0 && u < 64 * 128) {
            int nc = u >> 7, k = u & 127;
            W2t[u] = f2bf(W2[k * 64 + nc]);
        }
        return;
    }
    __shared__ int2 pairs[PB];          // 32 KB
    __shared__ int hist[512];
    __shared__ int base[512];
    int t = threadIdx.x;
    int e0 = blockIdx.x * PB;
    int cnt = min(PB, E - e0);
    for (int b = t; b < NB; b += 256) hist[b] = 0;
    __syncthreads();
    for (int i = t; i < cnt; i += 256) {
        int s = src[e0 + i], d = dst[e0 + i];
        pairs[i] = make_int2(s, d);
        atomicAdd(&hist[d >> BSH], 1);
    }
    __syncthreads();
    for (int b = t; b < NB; b += 256) {
        int h = hist[b];
        int gb = (h > 0) ? atomicAdd(&bcur[b], h) : 0;
        base[b] = b * CAP + gb;
        hist[b] = 0;
    }
    __syncthreads();
    for (int i = t; i < cnt; i += 256) {
        int2 p = pairs[i];
        int b = p.y >> BSH;
        int q = base[b] + atomicAdd(&hist[b], 1);
        pairBuf[q] = p;
    }
}

__global__ __launch_bounds__(256) void bucket_build(
    const int2* __restrict__ pairBuf, const int* __restrict__ bcur,
    int* __restrict__ rowptr, int* __restrict__ deg, float* __restrict__ dinv,
    int* __restrict__ csr, int N) {
    __shared__ int cnt[256];
    __shared__ int loc[256];
    int b = blockIdx.x, t = threadIdx.x;
    int start = b * CAP, end = start + bcur[b];
    cnt[t] = 0;
    __syncthreads();
    for (int i = start + t; i < end; i += 256)
        atomicAdd(&cnt[pairBuf[i].y & 255], 1);
    __syncthreads();
    int v = cnt[t];
    loc[t] = v;
    __syncthreads();
    for (int o = 1; o < 256; o <<= 1) {
        int add = (t >= o) ? loc[t - o] : 0;
        __syncthreads();
        loc[t] += add;
        __syncthreads();
    }
    int excl = loc[t] - v;
    int node = (b << BSH) + t;
    if (node < N) {
        rowptr[node] = start + excl;
        deg[node] = v;
        dinv[node] = rsqrtf((float)(v + 2));   // +2 self-loops
    }
    __syncthreads();
    cnt[t] = excl;                              // reuse as cursor
    __syncthreads();
    for (int i = start + t; i < end; i += 256) {
        int2 p = pairBuf[i];
        int q = start + atomicAdd(&cnt[p.y & 255], 1);
        csr[q] = p.x;
    }
}

// ---------------- MFMA GEMM1: H1[n,128] = fp8(dinv[n] * (x[n,128] @ W1)) ----------
// m97-style staging (global_load_lds width=16, register-free) + OPERAND-SWAPPED
// MFMA: acc[nt][p] holds 4 CONSECUTIVE channels of ONE node -> dword fp8 stores.

__global__ __launch_bounds__(256) void gemm1_mfma(
    const float* __restrict__ A, const unsigned short* __restrict__ Wt,
    const float* __restrict__ dinv, uchar* __restrict__ C, int n, int nTiles) {
    constexpr int NT = 8;                          // 128 out channels / 16
    __shared__ unsigned short Ws[128 * 136];       // padded W (34.8K)
    __shared__ char As[64 * 512];                  // 64-row fp32 tile (32K)

    const int t = threadIdx.x;

    // stage W once (padded pitch kills ds_read bank conflicts)
    for (int i = t; i < 128 * 16; i += 256) {
        int rr = i >> 4, sq = i & 15;
        *(uint4*)&Ws[rr * 136 + sq * 8] = *(const uint4*)(Wt + rr * 128 + sq * 8);
    }

    const int w = t >> 6, l = t & 63;
    const int q = l >> 4, r16 = l & 15;
    const int rw = w * 16 + r16;                   // this lane's node row in tile

    for (int tile = blockIdx.x; tile < nTiles; tile += gridDim.x) {
        const int row0 = tile * 64;

        // ---- stage A tile: linear LDS dest, per-lane clamped global source ----
#pragma unroll
        for (int rnd = 0; rnd < 8; rnd++) {
            int p = rnd * 4096 + t * 16;           // byte position in tile
            int row = row0 + (p >> 9);
            int col = p & 511;
            gload16((const char*)A + (size_t)min(row, n - 1) * 512 + col, As + p);
        }
        __syncthreads();   // drains vmcnt -> tile resident (and W on first iter)

        f32x4 acc[NT];
#pragma unroll
        for (int i = 0; i < NT; i++) acc[i] = (f32x4){0.f, 0.f, 0.f, 0.f};

#pragma unroll
        for (int s = 0; s < 4; s++) {
            const int k0 = s * 32 + q * 8;         // element k-offset
            // x-fragment (B operand: lane&15 -> node col)
            const float* Arow = (const float*)(As + rw * 512);
            float4 v0 = *(const float4*)(Arow + k0);
            float4 v1 = *(const float4*)(Arow + k0 + 4);
            bf16x8 xf;
            xf[0] = (short)f2bf(v0.x); xf[1] = (short)f2bf(v0.y);
            xf[2] = (short)f2bf(v0.z); xf[3] = (short)f2bf(v0.w);
            xf[4] = (short)f2bf(v1.x); xf[5] = (short)f2bf(v1.y);
            xf[6] = (short)f2bf(v1.z); xf[7] = (short)f2bf(v1.w);
#pragma unroll
            for (int nt = 0; nt < NT; nt++) {
                // W-fragment (A operand: lane&15 -> channel row)
                bf16x8 wf = *(const bf16x8*)&Ws[(nt * 16 + r16) * 136 + k0];
                acc[nt] = __builtin_amdgcn_mfma_f32_16x16x32_bf16(wf, xf, acc[nt], 0, 0, 0);
            }
        }

        // ---- epilogue: acc[nt][p] = channel (nt*16 + q*4 + p) of node rw ----
        const int node = row0 + rw;
        const bool nv = node < n;
        const float dv = dinv[min(node, n - 1)];
        uchar* Crow = C + (size_t)node * 128;
#pragma unroll
        for (int nt = 0; nt < NT; nt++) {
            int pk = 0;
            pk = __builtin_amdgcn_cvt_pk_fp8_f32(acc[nt][0] * dv, acc[nt][1] * dv, pk, false);
            pk = __builtin_amdgcn_cvt_pk_fp8_f32(acc[nt][2] * dv, acc[nt][3] * dv, pk, true);
            if (nv) *(uint32*)(Crow + nt * 16 + q * 4) = (uint32)pk;
        }
        __syncthreads();   // protect As from next tile's staging
    }
}

// ---------------- Fused agg1 + gemm2: pipelined LDS-staged gather ---------------
// Per 16-edge batch: issue 8x global_load_lds (8 KB, zero VGPR), then issue the
// NEXT batch's csr index load, then SPLIT-DRAIN: vmcnt(4) -> consume edges 0..7
// while edges 8..15 are still in flight; vmcnt(0) -> consume the rest. vmcnt(4)
// guarantees the oldest gloads 0..3 are complete regardless of where the csr
// load lands in issue order (FIFO vmcnt semantics).

__global__ __launch_bounds__(256) void agg1_fused(
    const uchar* __restrict__ H, const int* __restrict__ csr,
    const int* __restrict__ rowptr, const int* __restrict__ deg,
    const float* __restrict__ dinv, const float* __restrict__ bias,
    const unsigned short* __restrict__ W2t, uchar* __restrict__ H2, int n) {
    __shared__ char stage[4][8192];                // per-wave gather slices
    __shared__ unsigned short tile[16 * 136];      // 16 nodes x 128ch bf16, padded
    int t = threadIdx.x;
    int slot = t >> 4;                              // node slot in block (0..15)
    int v = blockIdx.x * 16 + slot;
    int hl = t & 15;
    int gsel = t & 48;
    int w = t >> 6;                                 // wave id
    int gg = (t >> 4) & 3;                          // group within wave
    bool valid = v < n;
    int vc = valid ? v : 0;
    int base = rowptr[vc];
    int cnt = valid ? deg[vc] : 0;

    f32x2 A0 = (f32x2){0.f, 0.f}, A1 = A0, A2 = A0, A3 = A0;
    f32x2 B0 = A0, B1 = A0, B2 = A0, B3 = A0;

#define ACC128(h, s0, s1, s2, s3)                                   \
    {                                                               \
        s0 += __builtin_amdgcn_cvt_pk_f32_fp8((h).x, false);        \
        s1 += __builtin_amdgcn_cvt_pk_f32_fp8((h).x, true);         \
        s2 += __builtin_amdgcn_cvt_pk_f32_fp8((h).y, false);        \
        s3 += __builtin_amdgcn_cvt_pk_f32_fp8((h).y, true);         \
    }

    char* sl = stage[w];
    const char* rg = sl + gg * 256 + hl * 8;       // consume base for this lane

    int ul = 0;
    if (hl < min(16, cnt)) ul = csr[base + hl];    // batch 0 indices

    for (int j0 = 0; j0 < cnt; j0 += 16) {
        int nj = min(16, cnt - j0);
        // ---- issue: 8x global_load_lds (8 KB in flight, no VGPR held) ----
#pragma unroll
        for (int i = 0; i < 8; i++) {
            int j = i * 2 + (hl >> 3);
            int u = __shfl(ul, j | gsel);
            gload16(H + (((uint32)u << 7) + ((uint32)(hl & 7) << 4)),
                    sl + i * 1024);
        }
        // ---- prefetch next batch's csr indices (drains under consume) ----
        int ul2 = 0;
        int j0n = j0 + 16;
        if (j0n < cnt && hl < min(16, cnt - j0n)) ul2 = csr[base + j0n + hl];
        // ---- split-drain consume ----
        asm volatile("s_waitcnt vmcnt(4)" ::: "memory");
        __builtin_amdgcn_sched_barrier(0);
#pragma unroll
        for (int j = 0; j < 8; j++) {
            if (j < nj) {
                uint2 h = *(const uint2*)(rg + (j >> 1) * 1024 + (j & 1) * 128);
                if (j & 1) { ACC128(h, B0, B1, B2, B3); }
                else       { ACC128(h, A0, A1, A2, A3); }
            }
        }
        asm volatile("s_waitcnt vmcnt(0)" ::: "memory");
        __builtin_amdgcn_sched_barrier(0);
#pragma unroll
        for (int j = 8; j < 16; j++) {
            if (j < nj) {
                uint2 h = *(const uint2*)(rg + (j >> 1) * 1024 + (j & 1) * 128);
                if (j & 1) { ACC128(h, B0, B1, B2, B3); }
                else       { ACC128(h, A0, A1, A2, A3); }
            }
        }
        ul = ul2;
    }
#undef ACC128

    // ---- finish hidden: self-loop + bias + ReLU, pack bf16 ----
    const uint32 co = (uint32)(hl * 8);
    uint4 pk = make_uint4(0, 0, 0, 0);
    if (valid) {
        float dv = dinv[vc];
        uint2 hv = *(const uint2*)(H + (((uint32)vc << 7) + co));
        f32x2 s0 = __builtin_amdgcn_cvt_pk_f32_fp8(hv.x, false);
        f32x2 s1 = __builtin_amdgcn_cvt_pk_f32_fp8(hv.x, true);
        f32x2 s2 = __builtin_amdgcn_cvt_pk_f32_fp8(hv.y, false);
        f32x2 s3 = __builtin_amdgcn_cvt_pk_f32_fp8(hv.y, true);
        const f32x2* bp = (const f32x2*)(bias + hl * 8);
        f32x2 e0 = dv * ((A0 + B0) + 2.f * s0) + bp[0];
        f32x2 e1 = dv * ((A1 + B1) + 2.f * s1) + bp[1];
        f32x2 e2 = dv * ((A2 + B2) + 2.f * s2) + bp[2];
        f32x2 e3 = dv * ((A3 + B3) + 2.f * s3) + bp[3];
        float o0 = fmaxf(e0[0], 0.f), o1 = fmaxf(e0[1], 0.f);
        float o2 = fmaxf(e1[0], 0.f), o3 = fmaxf(e1[1], 0.f);
        float o4 = fmaxf(e2[0], 0.f), o5 = fmaxf(e2[1], 0.f);
        float o6 = fmaxf(e3[0], 0.f), o7 = fmaxf(e3[1], 0.f);
        pk.x = (uint32)f2bf(o0) | ((uint32)f2bf(o1) << 16);
        pk.y = (uint32)f2bf(o2) | ((uint32)f2bf(o3) << 16);
        pk.z = (uint32)f2bf(o4) | ((uint32)f2bf(o5) << 16);
        pk.w = (uint32)f2bf(o6) | ((uint32)f2bf(o7) << 16);
    }
    *(uint4*)&tile[slot * 136 + hl * 8] = pk;
    __syncthreads();

    // ---- gemm2 tail: wave w -> channels w*16..+15 for all 16 nodes ----
    const int l = t & 63;
    const int q = l >> 4, r16 = l & 15;
    f32x4 acc2 = (f32x4){0.f, 0.f, 0.f, 0.f};
#pragma unroll
    for (int s = 0; s < 4; s++) {
        const int k0 = s * 32 + q * 8;
        bf16x8 hf = *(const bf16x8*)&tile[r16 * 136 + k0];                 // node r16
        bf16x8 wf = *(const bf16x8*)(W2t + (size_t)(w * 16 + r16) * 128 + k0); // channel
        acc2 = __builtin_amdgcn_mfma_f32_16x16x32_bf16(wf, hf, acc2, 0, 0, 0);
    }
    const int node = blockIdx.x * 16 + r16;
    if (node < n) {
        const float dv2 = dinv[node];
        int pk2 = 0;
        pk2 = __builtin_amdgcn_cvt_pk_fp8_f32(acc2[0] * dv2, acc2[1] * dv2, pk2, false);
        pk2 = __builtin_amdgcn_cvt_pk_fp8_f32(acc2[2] * dv2, acc2[3] * dv2, pk2, true);
        *(uint32*)(H2 + (size_t)node * 64 + w * 16 + q * 4) = (uint32)pk2;
    }
}

// agg2: 64 ch; same pipelined LDS-staged gather (4 gloads/batch + csr prefetch,
// vmcnt(2)/vmcnt(0) split). log_softmax within group of 16.
__global__ __launch_bounds__(256) void agg_lsm_64(
    const uchar* __restrict__ H, const int* __restrict__ csr,
    const int* __restrict__ rowptr, const int* __restrict__ deg,
    const float* __restrict__ dinv, const float* __restrict__ bias,
    float* __restrict__ out, int n) {
    __shared__ char stage[4][4096];
    int t = threadIdx.x;
    int v = blockIdx.x * 16 + (t >> 4);
    int hl = t & 15;
    int gsel = t & 48;
    int w = t >> 6;
    int gg = (t >> 4) & 3;
    bool valid = v < n;
    int vc = valid ? v : 0;
    int base = rowptr[vc];
    int cnt = valid ? deg[vc] : 0;
    const uint32 co = (uint32)(hl * 4);

    f32x2 A0 = (f32x2){0.f, 0.f}, A1 = A0, B0 = A0, B1 = A0;

#define ACC64(h, s0, s1)                                            \
    {                                                               \
        s0 += __builtin_amdgcn_cvt_pk_f32_fp8((h), false);          \
        s1 += __builtin_amdgcn_cvt_pk_f32_fp8((h), true);           \
    }

    char* sl = stage[w];
    const char* rg = sl + gg * 256 + hl * 4;

    int ul = 0;
    if (hl < min(16, cnt)) ul = csr[base + hl];

    for (int j0 = 0; j0 < cnt; j0 += 16) {
        int nj = min(16, cnt - j0);
#pragma unroll
        for (int i = 0; i < 4; i++) {
            int j = i * 4 + (hl >> 2);
            int u = __shfl(ul, j | gsel);
            gload16(H + (((uint32)u << 6) + ((uint32)(hl & 3) << 4)),
                    sl + i * 1024);
        }
        int ul2 = 0;
        int j0n = j0 + 16;
        if (j0n < cnt && hl < min(16, cnt - j0n)) ul2 = csr[base + j0n + hl];
        asm volatile("s_waitcnt vmcnt(2)" ::: "memory");
        __builtin_amdgcn_sched_barrier(0);
#pragma unroll
        for (int j = 0; j < 8; j++) {
            if (j < nj) {
                uint32 h = *(const uint32*)(rg + (j >> 2) * 1024 + (j & 3) * 64);
                if (j & 1) { ACC64(h, B0, B1); }
                else       { ACC64(h, A0, A1); }
            }
        }
        asm volatile("s_waitcnt vmcnt(0)" ::: "memory");
        __builtin_amdgcn_sched_barrier(0);
#pragma unroll
        for (int j = 8; j < 16; j++) {
            if (j < nj) {
                uint32 h = *(const uint32*)(rg + (j >> 2) * 1024 + (j & 3) * 64);
                if (j & 1) { ACC64(h, B0, B1); }
                else       { ACC64(h, A0, A1); }
            }
        }
        ul = ul2;
    }
#undef ACC64

    float dv = dinv[vc];
    uint32 hv = *(const uint32*)(H + (((uint32)vc << 6) + co));
    f32x2 s0 = __builtin_amdgcn_cvt_pk_f32_fp8(hv, false);
    f32x2 s1 = __builtin_amdgcn_cvt_pk_f32_fp8(hv, true);
    const f32x2* bp = (const f32x2*)(bias + hl * 4);
    f32x2 w0 = dv * ((A0 + B0) + 2.f * s0) + bp[0];
    f32x2 w1 = dv * ((A1 + B1) + 2.f * s1) + bp[1];
    float v0 = w0[0], v1 = w0[1], v2 = w1[0], v3 = w1[1];
    // log_softmax across the 64 channels held by this 16-lane group
    float m = fmaxf(fmaxf(v0, v1), fmaxf(v2, v3));
    for (int o = 8; o > 0; o >>= 1) m = fmaxf(m, __shfl_xor(m, o));
    float e = (__expf(v0 - m) + __expf(v1 - m)) + (__expf(v2 - m) + __expf(v3 - m));
    for (int o = 8; o > 0; o >>= 1) e += __shfl_xor(e, o);
    float ls = m + __logf(e);
    if (valid)
        *(float4*)(out + (size_t)vc * 64 + hl * 4) =
            make_float4(v0 - ls, v1 - ls, v2 - ls, v3 - ls);
}

// ---------------- launch ----------------

extern "C" void kernel_launch(void* const* d_in, const int* in_sizes, int n_in,
                              void* d_out, int out_size, void* d_ws, size_t ws_size,
                              hipStream_t stream) {
    const float* x  = (const float*)d_in[0];
    const int*   ei = (const int*)d_in[1];
    const float* W1 = (const float*)d_in[2];
    const float* b1 = (const float*)d_in[3];
    const float* W2 = (const float*)d_in[4];
    const float* b2 = (const float*)d_in[5];
    float* out = (float*)d_out;

    const int N = in_sizes[0] / IN_CH;  // 100000
    const int E = in_sizes[1] / 2;      // 1600000
    const int* src = ei;
    const int* dst = ei + E;
    const int NB = (N + 255) >> BSH;    // 391 buckets

    char* w = (char*)d_ws;
    size_t off = 0;
    auto alloc = [&](size_t bytes) -> char* {
        char* p = w + off;
        off = (off + bytes + 255) & ~(size_t)255;
        return p;
    };
    int*   deg    = (int*)alloc((size_t)N * 4);
    int*   rowptr = (int*)alloc((size_t)N * 4);
    int*   bcur   = (int*)alloc(512 * 4);
    float* dinv   = (float*)alloc((size_t)N * 4 + 1024);  // +pad for vector tails
    int*   csr    = (int*)alloc((size_t)NB * CAP * 4);    // segmented, 9.6 MB
    unsigned short* W1t = (unsigned short*)alloc(128 * 128 * 2);
    unsigned short* W2t = (unsigned short*)alloc(64 * 128 * 2);
    uchar* H1  = (uchar*)alloc((size_t)N * HID_CH);          // fp8, 12.8 MB
    char*  scratch = alloc((size_t)NB * CAP * 8);            // pairBuf then H2 (19.2 MB)
    uchar* H2  = (uchar*)scratch;        // fp8, 6.4 MB (pairBuf dead after bucket_build)
    int2*  pairBuf = (int2*)scratch;

    hipMemsetAsync(bcur, 0, 512 * 4, stream);

    int gP = (E + PB - 1) / PB;         // 391 partition blocks

    part1_wtrans<<<gP + 96, 256, 0, stream>>>(src, dst, bcur, pairBuf, E, NB, gP,
                                              W1, W2, W1t, W2t);
    bucket_build<<<NB, 256, 0, stream>>>(pairBuf, bcur, rowptr, deg, dinv, csr, N);

    const int nTiles = (N + 63) / 64;   // 1563
    const int gG = min(nTiles, 512);    // persistent grid-stride blocks
    gemm1_mfma<<<gG, 256, 0, stream>>>(x, W1t, dinv, H1, N, nTiles);
    agg1_fused<<<(N + 15) / 16, 256, 0, stream>>>(H1, csr, rowptr, deg, dinv, b1, W2t, H2, N);
    agg_lsm_64<<<(N + 15) / 16, 256, 0, stream>>>(H2, csr, rowptr, deg, dinv, b2, out, N);
}